// Round 2
// baseline (2328.068 us; speedup 1.0000x reference)
//
#include <hip/hip_runtime.h>

#define DEV __device__ __forceinline__

typedef __bf16 bf16x8 __attribute__((ext_vector_type(8)));
typedef float f32x4 __attribute__((ext_vector_type(4)));

union U8 { uint4 q; unsigned short u[8]; };

constexpr int BN = 4, H = 270, W = 512, HW = H * W;
constexpr int IH5 = 274, P5 = 516;   // pad-2 buffers (SIFT descriptor)
constexpr int IH3 = 272, P3 = 514;   // pad-1 buffers

DEV unsigned short f2bf(float f) {
  unsigned int u = __builtin_bit_cast(unsigned int, f);
  u = (u + 0x7FFFu + ((u >> 16) & 1u)) >> 16;
  return (unsigned short)u;
}
DEV float bf2f(unsigned short h) {
  return __builtin_bit_cast(float, (unsigned int)h << 16);
}

// ---------------------------------------------------------------- diagnostic
__global__ void k_fill(float* __restrict__ out, int n, float v) {
  int i = blockIdx.x * 256 + threadIdx.x;
  if (i < n) out[i] = v;
}

// ---------------------------------------------------------------- SIFT stage 1
__global__ void k_sift_ang(const float* __restrict__ x, float* __restrict__ ang, int nTot) {
  int p = blockIdx.x * 256 + threadIdx.x;
  if (p >= nTot) return;
  int b = p / HW, r = p % HW, y = r / W, xx = r % W;
  const float* xb = x + (size_t)b * HW;
  float xm = xb[y * W + (xx > 0 ? xx - 1 : 0)];
  float xp = xb[y * W + (xx < W - 1 ? xx + 1 : W - 1)];
  float ym = xb[(y > 0 ? y - 1 : 0) * W + xx];
  float yp = xb[(y < H - 1 ? y + 1 : H - 1) * W + xx];
  float gx = (xp - xm) * 0.5f, gy = (yp - ym) * 0.5f;
  float mag = sqrtf(gx * gx + gy * gy + 1e-10f);
  float ori = atan2f(gy, gx + 1e-10f) + 6.2831855f;
  float o = (8.0f * ori) / 6.2831855f;
  float bo0f = floorf(o);
  float wo1 = o - bo0f;
  int b0 = ((int)bo0f) & 7;
  int b1 = (b0 + 1) & 7;
  float w0m = (1.0f - wo1) * mag, w1m = wo1 * mag;
  float v[8];
#pragma unroll
  for (int k = 0; k < 8; ++k)
    v[k] = (k == b0 ? w0m : 0.0f) + (k == b1 ? w1m : 0.0f);
  float4* o4 = (float4*)(ang + (size_t)p * 8);
  o4[0] = make_float4(v[0], v[1], v[2], v[3]);
  o4[1] = make_float4(v[4], v[5], v[6], v[7]);
}

// ---------------------------------------------------------------- SIFT stage 2
__global__ void k_sift_pool(const float* __restrict__ ang, float* __restrict__ pooled, int nTot) {
  constexpr int PH = H + 1, PW = W + 1;
  int p = blockIdx.x * 256 + threadIdx.x;
  if (p >= nTot) return;
  int b = p / (PH * PW), r = p % (PH * PW), y = r / PW, xx = r % PW;
  float4 a0 = {0, 0, 0, 0}, a1 = {0, 0, 0, 0};
  const float xc2[4] = {0.5f, 1.5f, 1.5f, 0.5f};
#pragma unroll
  for (int ky = 0; ky < 4; ++ky) {
    int yy = y - 2 + ky;
    if (yy < 0 || yy >= H) continue;
#pragma unroll
    for (int kx = 0; kx < 4; ++kx) {
      int xs = xx - 2 + kx;
      if (xs < 0 || xs >= W) continue;
      float w = xc2[ky] * xc2[kx] * 0.25f;
      const float4* s4 = (const float4*)(ang + ((size_t)(b * H + yy) * W + xs) * 8);
      float4 v0 = s4[0], v1 = s4[1];
      a0.x += w * v0.x; a0.y += w * v0.y; a0.z += w * v0.z; a0.w += w * v0.w;
      a1.x += w * v1.x; a1.y += w * v1.y; a1.z += w * v1.z; a1.w += w * v1.w;
    }
  }
  float4* o4 = (float4*)(pooled + (size_t)p * 8);
  o4[0] = a0; o4[1] = a1;
}

// ---------------------------------------------------------------- SIFT stage 3
// one wave per pixel; lane l handles channels 2l, 2l+1 (c = a*16 + (dy*4+dx))
__global__ void k_sift_desc(const float* __restrict__ pooled, unsigned short* __restrict__ spad) {
  constexpr int PH = H + 1, PW = W + 1;
  int tid = threadIdx.x;
  int wv = tid >> 6, lane = tid & 63;
  int p = blockIdx.x * 4 + wv;
  int b = p / HW, r = p % HW, yy = r / W, xx = r % W;
  int a = lane >> 3, jj = lane & 7;
  int j0 = jj * 2;
  int dy = j0 >> 2, dx = j0 & 3;
  int rr = yy + dy - 1;
  int c0 = xx + dx - 1, c1 = c0 + 1;
  bool rv = (rr >= 0 && rr <= H);
  int rc = min(max(rr, 0), H);
  const float* pb = pooled + ((size_t)(b * PH + rc) * PW) * 8 + a;
  float v0 = 0.0f, v1 = 0.0f;
  if (rv && c0 >= 0 && c0 <= W) v0 = pb[(size_t)c0 * 8];
  if (rv && c1 >= 0 && c1 <= W) v1 = pb[(size_t)c1 * 8];

  float n2 = v0 * v0 + v1 * v1;
#pragma unroll
  for (int m = 1; m < 64; m <<= 1) n2 += __shfl_xor(n2, m);
  float inv = 1.0f / fmaxf(sqrtf(n2), 1e-12f);
  v0 = fminf(v0 * inv, 0.2f);
  v1 = fminf(v1 * inv, 0.2f);
  float n2b = v0 * v0 + v1 * v1;
#pragma unroll
  for (int m = 1; m < 64; m <<= 1) n2b += __shfl_xor(n2b, m);
  inv = 1.0f / fmaxf(sqrtf(n2b), 1e-12f);
  v0 *= inv; v1 *= inv;
  float l1 = v0 + v1;
#pragma unroll
  for (int m = 1; m < 64; m <<= 1) l1 += __shfl_xor(l1, m);
  float il1 = 1.0f / fmaxf(l1, 1e-12f);
  v0 = sqrtf(v0 * il1 + 1e-10f);
  v1 = sqrtf(v1 * il1 + 1e-10f);
  unsigned int pk = (unsigned int)f2bf(v0) | ((unsigned int)f2bf(v1) << 16);
  *(unsigned int*)(spad + ((size_t)(b * IH5 + yy + 2) * P5 + xx + 2) * 128 + lane * 2) = pk;
}

// ---------------------------------------------------------------- weight prep: [t][co][ci] bf16
template <int CIN, int COUT, int KS>
__global__ void k_prep(const float* __restrict__ w, unsigned short* __restrict__ wbuf) {
  int i = blockIdx.x * 256 + threadIdx.x;
  if (i >= KS * KS * COUT * CIN) return;
  int t = i / (COUT * CIN), r2 = i % (COUT * CIN), co = r2 / CIN, e = r2 % CIN;
  wbuf[i] = f2bf(w[(co * CIN + e) * (KS * KS) + t]);
}

// ---------------------------------------------------------------- MFMA implicit-GEMM conv
// NHWC padded input, 128-px strip per block, all COUT channels, bf16 in / f32 acc.
template <int CIN, int COUT, int KS, int NG, int PADOFF>
__launch_bounds__(256)
__global__ void k_conv_mfma(const unsigned short* __restrict__ in, int IHt, int ipitch,
                            const unsigned short* __restrict__ wbuf,
                            const float* __restrict__ bias,
                            unsigned short* __restrict__ outraw,
                            float* __restrict__ part) {
  constexpr int BM = 128;
  constexpr int R = CIN * 2;          // bytes per row (pixel/co) in LDS
  constexpr int SA = BM * R;
  constexpr int SW = COUT * R;
  constexpr int KSTEPS = CIN / 32;
  constexpr int NF = COUT / 16;
  constexpr int SWZM = (R / 16) >= 8 ? 7 : (R / 16) - 1;
  constexpr int NIA = SA / 4096;
  constexpr int NIW = (SW + 4095) / 4096;
  __shared__ __align__(16) unsigned char smem[SA + SW];
  __shared__ float red[4][16];

  int tid = threadIdx.x;
  int lane = tid & 63, wv = tid >> 6;
  int l15 = lane & 15, hi = lane >> 4;
  int bid = blockIdx.x;
  int xt = bid & 3, rem = bid >> 2;
  int y = rem % H, b = rem / H;
  int x0 = xt * BM;

  f32x4 acc[2][NF] = {};
  uint4 rA[NIA], rW[NIW];

  auto load_tap = [&](int t) {
    int ky = t / KS, kx = t % KS;
    const char* src = (const char*)(in + ((size_t)(b * IHt + y + ky + PADOFF) * ipitch + (x0 + kx + PADOFF)) * CIN);
    const char* wsrc = (const char*)(wbuf + (size_t)t * (SW / 2));
#pragma unroll
    for (int i = 0; i < NIA; ++i)
      rA[i] = *(const uint4*)(src + tid * 16 + i * 4096);
#pragma unroll
    for (int i = 0; i < NIW; ++i) {
      int d = tid * 16 + i * 4096;
      if ((SW & 4095) == 0 || d < SW) rW[i] = *(const uint4*)(wsrc + d);
    }
  };

  load_tap(0);
#pragma unroll 1
  for (int t = 0; t < KS * KS; ++t) {
    __syncthreads();   // previous tap's LDS reads complete
#pragma unroll
    for (int i = 0; i < NIA; ++i) {
      int d = tid * 16 + i * 4096;
      int px = d / R, q = d & (R - 1);
      *(uint4*)(smem + px * R + (q ^ ((px & SWZM) << 4))) = rA[i];
    }
#pragma unroll
    for (int i = 0; i < NIW; ++i) {
      int d = tid * 16 + i * 4096;
      if ((SW & 4095) == 0 || d < SW) {
        int co = d / R, q = d & (R - 1);
        *(uint4*)(smem + SA + co * R + (q ^ ((co & SWZM) << 4))) = rW[i];
      }
    }
    __syncthreads();
    if (t + 1 < KS * KS) load_tap(t + 1);   // prefetch next tap under compute
#pragma unroll
    for (int ks = 0; ks < KSTEPS; ++ks) {
      int koff = ks * 64 + hi * 16;
      bf16x8 af[2], bq[NF];
#pragma unroll
      for (int mi = 0; mi < 2; ++mi) {
        int px = wv * 32 + mi * 16 + l15;
        af[mi] = *(const bf16x8*)(smem + px * R + (koff ^ ((px & SWZM) << 4)));
      }
#pragma unroll
      for (int ni = 0; ni < NF; ++ni) {
        int co = ni * 16 + l15;
        bq[ni] = *(const bf16x8*)(smem + SA + co * R + (koff ^ ((co & SWZM) << 4)));
      }
#pragma unroll
      for (int mi = 0; mi < 2; ++mi)
#pragma unroll
        for (int ni = 0; ni < NF; ++ni)
          acc[mi][ni] = __builtin_amdgcn_mfma_f32_16x16x32_bf16(af[mi], bq[ni], acc[mi][ni], 0, 0, 0);
    }
  }

  // bias
#pragma unroll
  for (int ni = 0; ni < NF; ++ni) {
    float bv = bias[ni * 16 + l15];
#pragma unroll
    for (int mi = 0; mi < 2; ++mi)
#pragma unroll
      for (int rr = 0; rr < 4; ++rr)
        acc[mi][ni][rr] += bv;
  }
  // store raw NHWC bf16
  unsigned short* op = outraw + ((size_t)(b * H + y) * W + x0) * COUT;
#pragma unroll
  for (int mi = 0; mi < 2; ++mi)
#pragma unroll
    for (int rr = 0; rr < 4; ++rr) {
      int px = wv * 32 + mi * 16 + hi * 4 + rr;
#pragma unroll
      for (int ni = 0; ni < NF; ++ni)
        op[(size_t)px * COUT + ni * 16 + l15] = f2bf(acc[mi][ni][rr]);
    }
  // deterministic per-block GN partials
  if constexpr (NG > 0) {
    constexpr int GPC = COUT / NG;
#pragma unroll
    for (int ni = 0; ni < NF; ++ni) {
      float s = 0.0f, q = 0.0f;
#pragma unroll
      for (int mi = 0; mi < 2; ++mi)
#pragma unroll
        for (int rr = 0; rr < 4; ++rr) {
          float v = acc[mi][ni][rr];
          s += v; q += v * v;
        }
      s += __shfl_xor(s, 16); q += __shfl_xor(q, 16);
      s += __shfl_xor(s, 32); q += __shfl_xor(q, 32);
#pragma unroll
      for (int m = 1; m < GPC; m <<= 1) { s += __shfl_xor(s, m); q += __shfl_xor(q, m); }
      if (hi == 0 && (l15 % GPC) == 0) {
        int g = ni * (16 / GPC) + l15 / GPC;
        red[wv][g] = s;
        red[wv][NG + g] = q;
      }
    }
    __syncthreads();
    if (tid < 2 * NG)
      part[(size_t)bid * (2 * NG) + tid] =
          red[0][tid] + red[1][tid] + red[2][tid] + red[3][tid];
  }
}

// ---------------------------------------------------------------- GN finalize
template <int COUT, int NG>
__global__ void k_gn_fin(const float* __restrict__ part, int NB,
                         const float* __restrict__ gw, const float* __restrict__ gb,
                         float* __restrict__ scale, float* __restrict__ shift, float invN) {
  constexpr int GPC = COUT / NG;
  int b = blockIdx.x / NG, g = blockIdx.x % NG;
  int lane = threadIdx.x;
  float s = 0.0f, q = 0.0f;
  for (int i = lane; i < NB; i += 64) {
    const float* pp = part + (size_t)(b * NB + i) * (2 * NG);
    s += pp[g]; q += pp[NG + g];
  }
#pragma unroll
  for (int m = 1; m < 64; m <<= 1) { s += __shfl_xor(s, m); q += __shfl_xor(q, m); }
  if (lane == 0) {
    float mean = s * invN;
    float var = q * invN - mean * mean;
    float rstd = rsqrtf(var + 1e-5f);
#pragma unroll
    for (int j = 0; j < GPC; ++j) {
      int c = g * GPC + j;
      float sc = gw[c] * rstd;
      scale[b * COUT + c] = sc;
      shift[b * COUT + c] = gb[c] - mean * sc;
    }
  }
}

// ---------------------------------------------------------------- GN-apply (+ReLU, +skip) into padded buffer
template <int C, bool ADDSKIP>
__global__ void k_norm(const unsigned short* __restrict__ raw,
                       const unsigned short* __restrict__ skip,
                       const float* __restrict__ scale, const float* __restrict__ shift,
                       unsigned short* __restrict__ outpad) {
  int e = blockIdx.x * 256 + threadIdx.x;
  int idx = e * 8;
  int p = idx / C, c0 = idx % C;
  int b = p / HW, r = p % HW, y = r / W, xx = r % W;
  U8 v; v.q = *(const uint4*)(raw + (size_t)p * C + c0);
  U8 sk;
  if (ADDSKIP) sk.q = *(const uint4*)(skip + (size_t)p * C + c0);
  const float* sc = scale + b * C + c0;
  const float* sh = shift + b * C + c0;
  U8 o;
#pragma unroll
  for (int j = 0; j < 8; ++j) {
    float f = fmaxf(bf2f(v.u[j]) * sc[j] + sh[j], 0.0f);
    if (ADDSKIP) f += bf2f(sk.u[j]);
    o.u[j] = f2bf(f);
  }
  *(uint4*)(outpad + ((size_t)(b * IH3 + y + 1) * P3 + xx + 1) * C + c0) = o.q;
}

// ---------------------------------------------------------------- conv4 direct (16->8, 3x3) + GN partials
__global__ void k_conv4(const unsigned short* __restrict__ h3pad, const float* __restrict__ w4,
                        const float* __restrict__ b4, unsigned short* __restrict__ h4raw,
                        float* __restrict__ part) {
  __shared__ float wl[1152];
  __shared__ float red[4][8];
  for (int i = threadIdx.x; i < 1152; i += 256) {
    int t = i / 128, r2 = i % 128, ci = r2 >> 3, co = r2 & 7;
    wl[i] = w4[(co * 16 + ci) * 9 + t];
  }
  __syncthreads();
  int p = blockIdx.x * 256 + threadIdx.x;
  int b = p / HW, r = p % HW, y = r / W, xx = r % W;
  float acc[8];
#pragma unroll
  for (int co = 0; co < 8; ++co) acc[co] = b4[co];
#pragma unroll
  for (int t = 0; t < 9; ++t) {
    int ky = t / 3, kx = t % 3;
    const unsigned short* ip = h3pad + ((size_t)(b * IH3 + y + ky) * P3 + (xx + kx)) * 16;
    U8 u0, u1;
    u0.q = *(const uint4*)ip;
    u1.q = *(const uint4*)(ip + 8);
#pragma unroll
    for (int ci = 0; ci < 16; ++ci) {
      float iv = bf2f(ci < 8 ? u0.u[ci] : u1.u[ci - 8]);
#pragma unroll
      for (int co = 0; co < 8; ++co)
        acc[co] += iv * wl[t * 128 + ci * 8 + co];
    }
  }
  int lane = threadIdx.x & 63, wv = threadIdx.x >> 6;
  float s[4], q[4];
#pragma unroll
  for (int g = 0; g < 4; ++g) {
    s[g] = acc[2 * g] + acc[2 * g + 1];
    q[g] = acc[2 * g] * acc[2 * g] + acc[2 * g + 1] * acc[2 * g + 1];
  }
#pragma unroll
  for (int m = 1; m < 64; m <<= 1) {
#pragma unroll
    for (int g = 0; g < 4; ++g) { s[g] += __shfl_xor(s[g], m); q[g] += __shfl_xor(q[g], m); }
  }
  if (lane == 0) {
#pragma unroll
    for (int g = 0; g < 4; ++g) { red[wv][g] = s[g]; red[wv][4 + g] = q[g]; }
  }
  __syncthreads();
  if (threadIdx.x < 8)
    part[(size_t)blockIdx.x * 8 + threadIdx.x] =
        red[0][threadIdx.x] + red[1][threadIdx.x] + red[2][threadIdx.x] + red[3][threadIdx.x];
  U8 o;
#pragma unroll
  for (int co = 0; co < 8; ++co) o.u[co] = f2bf(acc[co]);
  *(uint4*)(h4raw + (size_t)p * 8) = o.q;
}

// ---------------------------------------------------------------- norm4 + skip2 (1x1 32->8) fused
__global__ void k_norm4(const unsigned short* __restrict__ h4raw, const unsigned short* __restrict__ blkpad,
                        const float* __restrict__ scale, const float* __restrict__ shift,
                        const float* __restrict__ sw2, const float* __restrict__ sb2,
                        unsigned short* __restrict__ blk2pad) {
  __shared__ float wl[256];
  {
    int i = threadIdx.x;
    int ci = i >> 3, co = i & 7;
    wl[i] = sw2[co * 32 + ci];
  }
  __syncthreads();
  int p = blockIdx.x * 256 + threadIdx.x;
  int b = p / HW, r = p % HW, y = r / W, xx = r % W;
  float acc[8];
#pragma unroll
  for (int co = 0; co < 8; ++co) acc[co] = sb2[co];
  size_t cbase = ((size_t)(b * IH3 + y + 1) * P3 + (xx + 1));
  const unsigned short* bp = blkpad + cbase * 32;
#pragma unroll
  for (int half = 0; half < 4; ++half) {
    U8 u; u.q = *(const uint4*)(bp + half * 8);
#pragma unroll
    for (int j = 0; j < 8; ++j) {
      float iv = bf2f(u.u[j]);
      int ci = half * 8 + j;
#pragma unroll
      for (int co = 0; co < 8; ++co) acc[co] += iv * wl[ci * 8 + co];
    }
  }
  U8 hv; hv.q = *(const uint4*)(h4raw + (size_t)p * 8);
  U8 o;
#pragma unroll
  for (int co = 0; co < 8; ++co) {
    float f = fmaxf(bf2f(hv.u[co]) * scale[b * 8 + co] + shift[b * 8 + co], 0.0f) + acc[co];
    o.u[co] = f2bf(f);
  }
  *(uint4*)(blk2pad + cbase * 8) = o.q;
}

// ---------------------------------------------------------------- conv5 direct (8->2, 3x3)
__global__ void k_conv5(const unsigned short* __restrict__ blk2pad, const float* __restrict__ w5,
                        const float* __restrict__ b5, float* __restrict__ h5) {
  __shared__ float wl[144];
  if (threadIdx.x < 144) {
    int i = threadIdx.x;
    int t = i / 16, r2 = i % 16, ci = r2 >> 1, co = r2 & 1;
    wl[i] = w5[(co * 8 + ci) * 9 + t];
  }
  __syncthreads();
  int p = blockIdx.x * 256 + threadIdx.x;
  int b = p / HW, r = p % HW, y = r / W, xx = r % W;
  float a0 = b5[0], a1 = b5[1];
#pragma unroll
  for (int t = 0; t < 9; ++t) {
    int ky = t / 3, kx = t % 3;
    const unsigned short* ip = blk2pad + ((size_t)(b * IH3 + y + ky) * P3 + (xx + kx)) * 8;
    U8 u; u.q = *(const uint4*)ip;
#pragma unroll
    for (int ci = 0; ci < 8; ++ci) {
      float iv = bf2f(u.u[ci]);
      a0 += iv * wl[t * 16 + ci * 2];
      a1 += iv * wl[t * 16 + ci * 2 + 1];
    }
  }
  h5[(size_t)p * 2] = a0;
  h5[(size_t)p * 2 + 1] = a1;
}

// ---------------------------------------------------------------- joint bilateral + tanh + scale
__global__ void k_bilateral(const float* __restrict__ h5, const float* __restrict__ x,
                            float* __restrict__ out, int nTot) {
  int p = blockIdx.x * 256 + threadIdx.x;
  if (p >= nTot) return;
  int b = p / HW, r = p % HW, y = r / W, xx = r % W;
  const float* xb = x + (size_t)b * HW;
  float xc = xb[r];
  float e1 = expf(-1.0f / 4.5f), e0 = expf(-4.0f / 4.5f);
  float gs = 1.0f + 2.0f * e1 + 2.0f * e0;
  float g[5] = {e0 / gs, e1 / gs, 1.0f / gs, e1 / gs, e0 / gs};
  float n0 = 0.0f, n1 = 0.0f, den = 0.0f;
#pragma unroll
  for (int dy = 0; dy < 5; ++dy) {
    int yn = y + dy - 2;
    yn = yn < 0 ? -yn : (yn >= H ? 2 * H - 2 - yn : yn);
#pragma unroll
    for (int dx = 0; dx < 5; ++dx) {
      int xn = xx + dx - 2;
      xn = xn < 0 ? -xn : (xn >= W ? 2 * W - 2 - xn : xn);
      float xv = xb[yn * W + xn];
      float d = xv - xc;
      float wgt = g[dy] * g[dx] * expf(-200.0f * d * d);
      den += wgt;
      const float* hp = h5 + ((size_t)(b * HW) + yn * W + xn) * 2;
      n0 += wgt * hp[0];
      n1 += wgt * hp[1];
    }
  }
  float o0 = tanhf(n0 / den) * 0.436f;
  float o1 = tanhf(n1 / den) * 0.615f;
  out[(size_t)(b * 2) * HW + r] = o0;
  out[(size_t)(b * 2 + 1) * HW + r] = o1;
}

// ---------------------------------------------------------------- host
extern "C" void kernel_launch(void* const* d_in, const int* in_sizes, int n_in,
                              void* d_out, int out_size, void* d_ws, size_t ws_size,
                              hipStream_t stream) {
  (void)in_sizes; (void)n_in; (void)out_size;
  const float* x   = (const float*)d_in[0];
  const float* w1  = (const float*)d_in[1];
  const float* b1  = (const float*)d_in[2];
  const float* g1w = (const float*)d_in[3];
  const float* g1b = (const float*)d_in[4];
  const float* w2  = (const float*)d_in[5];
  const float* b2  = (const float*)d_in[6];
  const float* g2w = (const float*)d_in[7];
  const float* g2b = (const float*)d_in[8];
  const float* w3  = (const float*)d_in[9];
  const float* b3  = (const float*)d_in[10];
  const float* g3w = (const float*)d_in[11];
  const float* g3b = (const float*)d_in[12];
  const float* w4  = (const float*)d_in[13];
  const float* b4  = (const float*)d_in[14];
  const float* g4w = (const float*)d_in[15];
  const float* g4b = (const float*)d_in[16];
  const float* w5  = (const float*)d_in[17];
  const float* b5  = (const float*)d_in[18];
  const float* sw1 = (const float*)d_in[19];
  const float* sb1 = (const float*)d_in[20];
  const float* sw2 = (const float*)d_in[21];
  const float* sb2 = (const float*)d_in[22];
  float* out = (float*)d_out;
  char* ws = (char*)d_ws;

  auto AL = [](size_t v) { return (v + 255) & ~(size_t)255; };
  // per-sample byte strides
  const size_t sSPAD  = (size_t)IH5 * P5 * 128 * 2;
  const size_t sANG   = (size_t)HW * 8 * 4;
  const size_t sH1RAW = (size_t)HW * 64 * 2;
  const size_t sH1PAD = (size_t)IH3 * P3 * 64 * 2;
  const size_t sH2RAW = (size_t)HW * 32 * 2;
  const size_t sBLKP  = (size_t)IH3 * P3 * 32 * 2;
  const size_t sH3RAW = (size_t)HW * 16 * 2;
  const size_t sH3PAD = (size_t)IH3 * P3 * 16 * 2;
  const size_t sH4RAW = (size_t)HW * 8 * 2;
  const size_t sBLK2  = (size_t)IH3 * P3 * 8 * 2;
  const size_t sH5    = (size_t)HW * 2 * 4;

  // choose largest batch-chunk that fits the workspace
  int nb = 0;
  size_t offB = 0, offH1PAD = 0, offSmall = 0;
  for (int cand = 4; cand >= 1; cand >>= 1) {
    size_t oB   = AL((size_t)cand * sSPAD);
    size_t oH1P = AL(oB + (size_t)cand * sH1RAW);
    size_t oS   = AL(oH1P + (size_t)cand * sH1PAD);
    size_t need = oS + AL(512 * 1024)                 // wb1..wbs1
                     + AL((size_t)4 * 1080 * 16 * 4)  // partials (max)
                     + 4 * 4096;                      // scale/shift slots
    if (ws_size >= need) { nb = cand; offB = oB; offH1PAD = oH1P; offSmall = oS; break; }
  }
  if (nb == 0) {  // diagnostic: workspace too small even for 1-sample chunks
    k_fill<<<(BN * 2 * HW + 255) / 256, 256, 0, stream>>>(out, BN * 2 * HW, 123.0f);
    return;
  }

  // small-region carve
  size_t oWB1  = offSmall;
  size_t oWB2  = AL(oWB1 + 25 * 64 * 128 * 2);
  size_t oWB3  = AL(oWB2 + 9 * 32 * 64 * 2);
  size_t oWBS  = AL(oWB3 + 9 * 16 * 32 * 2);
  size_t oPART = AL(oWBS + 32 * 128 * 2);
  size_t oSC1  = AL(oPART + (size_t)4 * 1080 * 16 * 4);
  size_t oSC2  = oSC1 + 4096, oSC3 = oSC2 + 4096, oSC4 = oSC3 + 4096;

  unsigned short* wb1  = (unsigned short*)(ws + oWB1);
  unsigned short* wb2  = (unsigned short*)(ws + oWB2);
  unsigned short* wb3  = (unsigned short*)(ws + oWB3);
  unsigned short* wbs1 = (unsigned short*)(ws + oWBS);
  float* part = (float*)(ws + oPART);
  float* sc1 = (float*)(ws + oSC1); float* sh1 = sc1 + nb * 64;
  float* sc2 = (float*)(ws + oSC2); float* sh2 = sc2 + nb * 32;
  float* sc3 = (float*)(ws + oSC3); float* sh3 = sc3 + nb * 16;
  float* sc4 = (float*)(ws + oSC4); float* sh4 = sc4 + nb * 8;

  k_prep<128, 64, 5><<<800, 256, 0, stream>>>(w1, wb1);
  k_prep<64, 32, 3><<<72, 256, 0, stream>>>(w2, wb2);
  k_prep<32, 16, 3><<<18, 256, 0, stream>>>(w3, wb3);
  k_prep<128, 32, 1><<<16, 256, 0, stream>>>(sw1, wbs1);

  // tail-region offsets inside the (dead-after-skip1) spad region
  size_t t0 = AL((size_t)nb * sBLKP);             // h3raw
  size_t t1 = AL(t0 + (size_t)nb * sH3RAW);       // h3pad
  size_t t2 = AL(t1 + (size_t)nb * sH3PAD);       // h4raw
  size_t t3 = AL(t2 + (size_t)nb * sH4RAW);       // blk2pad
  size_t t4 = AL(t3 + (size_t)nb * sBLK2);        // h5

  for (int b0 = 0; b0 < BN; b0 += nb) {
    const float* x_c = x + (size_t)b0 * HW;
    float* out_c = out + (size_t)b0 * 2 * HW;
    unsigned short* spad   = (unsigned short*)(ws);
    float*          ang    = (float*)(ws + offB);
    float*          pooled = (float*)(ws + AL(offB + (size_t)nb * sANG));
    unsigned short* h1raw  = (unsigned short*)(ws + offB);
    unsigned short* h1pad  = (unsigned short*)(ws + offH1PAD);
    unsigned short* h2raw  = (unsigned short*)(ws + offB);
    unsigned short* sk1    = (unsigned short*)(ws + offB + (size_t)nb * sH2RAW);
    unsigned short* blkpad = (unsigned short*)(ws);
    unsigned short* h3raw  = (unsigned short*)(ws + t0);
    unsigned short* h3pad  = (unsigned short*)(ws + t1);
    unsigned short* h4raw  = (unsigned short*)(ws + t2);
    unsigned short* blk2   = (unsigned short*)(ws + t3);
    float*          h5     = (float*)(ws + t4);
    int nHW = nb * HW;

    hipMemsetAsync(spad, 0, (size_t)nb * sSPAD, stream);
    hipMemsetAsync(h1pad, 0, (size_t)nb * sH1PAD, stream);

    k_sift_ang<<<nb * 540, 256, 0, stream>>>(x_c, ang, nHW);
    int nPP = nb * (H + 1) * (W + 1);
    k_sift_pool<<<(nPP + 255) / 256, 256, 0, stream>>>(ang, pooled, nPP);
    k_sift_desc<<<nHW / 4, 256, 0, stream>>>(pooled, spad);

    k_conv_mfma<128, 64, 5, 8, 0><<<nb * 1080, 256, 0, stream>>>(spad, IH5, P5, wb1, b1, h1raw, part);
    k_gn_fin<64, 8><<<nb * 8, 64, 0, stream>>>(part, 1080, g1w, g1b, sc1, sh1, 1.0f / (8.0f * HW));
    k_norm<64, false><<<nb * 4320, 256, 0, stream>>>(h1raw, nullptr, sc1, sh1, h1pad);

    k_conv_mfma<64, 32, 3, 8, 0><<<nb * 1080, 256, 0, stream>>>(h1pad, IH3, P3, wb2, b2, h2raw, part);
    k_gn_fin<32, 8><<<nb * 8, 64, 0, stream>>>(part, 1080, g2w, g2b, sc2, sh2, 1.0f / (4.0f * HW));
    k_conv_mfma<128, 32, 1, 0, 2><<<nb * 1080, 256, 0, stream>>>(spad, IH5, P5, wbs1, sb1, sk1, nullptr);

    // spad is dead now; its region hosts blkpad + tail buffers
    hipMemsetAsync(blkpad, 0, (size_t)nb * sBLKP, stream);
    hipMemsetAsync(h3pad, 0, (size_t)nb * sH3PAD, stream);
    hipMemsetAsync(blk2, 0, (size_t)nb * sBLK2, stream);

    k_norm<32, true><<<nb * 2160, 256, 0, stream>>>(h2raw, sk1, sc2, sh2, blkpad);

    k_conv_mfma<32, 16, 3, 4, 0><<<nb * 1080, 256, 0, stream>>>(blkpad, IH3, P3, wb3, b3, h3raw, part);
    k_gn_fin<16, 4><<<nb * 4, 64, 0, stream>>>(part, 1080, g3w, g3b, sc3, sh3, 1.0f / (4.0f * HW));
    k_norm<16, false><<<nb * 1080, 256, 0, stream>>>(h3raw, nullptr, sc3, sh3, h3pad);

    k_conv4<<<nb * 540, 256, 0, stream>>>(h3pad, w4, b4, h4raw, part);
    k_gn_fin<8, 4><<<nb * 4, 64, 0, stream>>>(part, 540, g4w, g4b, sc4, sh4, 1.0f / (2.0f * HW));
    k_norm4<<<nb * 540, 256, 0, stream>>>(h4raw, blkpad, sc4, sh4, sw2, sb2, blk2);

    k_conv5<<<nb * 540, 256, 0, stream>>>(blk2, w5, b5, h5);
    k_bilateral<<<nb * 540, 256, 0, stream>>>(h5, x_c, out_c, nHW);
  }
}

// Round 3
// 2260.845 us; speedup vs baseline: 1.0297x; 1.0297x over previous
//
#include <hip/hip_runtime.h>

#define DEV __device__ __forceinline__

typedef __bf16 bf16x8 __attribute__((ext_vector_type(8)));
typedef float f32x4 __attribute__((ext_vector_type(4)));

union U8 { uint4 q; unsigned short u[8]; };

constexpr int BN = 4, H = 270, W = 512, HW = H * W;
constexpr int IH5 = 274, P5 = 516;   // pad-2 buffers (SIFT descriptor)
constexpr int IH3 = 272, P3 = 514;   // pad-1 buffers

DEV unsigned short f2bf(float f) {
  unsigned int u = __builtin_bit_cast(unsigned int, f);
  u = (u + 0x7FFFu + ((u >> 16) & 1u)) >> 16;
  return (unsigned short)u;
}
DEV float bf2f(unsigned short h) {
  return __builtin_bit_cast(float, (unsigned int)h << 16);
}

// ---------------------------------------------------------------- diagnostic
__global__ void k_fill(float* __restrict__ out, int n, float v) {
  int i = blockIdx.x * 256 + threadIdx.x;
  if (i < n) out[i] = v;
}

// ---------------------------------------------------------------- SIFT stage 1
__global__ void k_sift_ang(const float* __restrict__ x, float* __restrict__ ang, int nTot) {
  int p = blockIdx.x * 256 + threadIdx.x;
  if (p >= nTot) return;
  int b = p / HW, r = p % HW, y = r / W, xx = r % W;
  const float* xb = x + (size_t)b * HW;
  float xm = xb[y * W + (xx > 0 ? xx - 1 : 0)];
  float xp = xb[y * W + (xx < W - 1 ? xx + 1 : W - 1)];
  float ym = xb[(y > 0 ? y - 1 : 0) * W + xx];
  float yp = xb[(y < H - 1 ? y + 1 : H - 1) * W + xx];
  float gx = (xp - xm) * 0.5f, gy = (yp - ym) * 0.5f;
  float mag = sqrtf(gx * gx + gy * gy + 1e-10f);
  float ori = atan2f(gy, gx + 1e-10f) + 6.2831855f;
  float o = (8.0f * ori) / 6.2831855f;
  float bo0f = floorf(o);
  float wo1 = o - bo0f;
  int b0 = ((int)bo0f) & 7;
  int b1 = (b0 + 1) & 7;
  float w0m = (1.0f - wo1) * mag, w1m = wo1 * mag;
  float v[8];
#pragma unroll
  for (int k = 0; k < 8; ++k)
    v[k] = (k == b0 ? w0m : 0.0f) + (k == b1 ? w1m : 0.0f);
  float4* o4 = (float4*)(ang + (size_t)p * 8);
  o4[0] = make_float4(v[0], v[1], v[2], v[3]);
  o4[1] = make_float4(v[4], v[5], v[6], v[7]);
}

// ---------------------------------------------------------------- SIFT stage 2
__global__ void k_sift_pool(const float* __restrict__ ang, float* __restrict__ pooled, int nTot) {
  constexpr int PH = H + 1, PW = W + 1;
  int p = blockIdx.x * 256 + threadIdx.x;
  if (p >= nTot) return;
  int b = p / (PH * PW), r = p % (PH * PW), y = r / PW, xx = r % PW;
  float4 a0 = {0, 0, 0, 0}, a1 = {0, 0, 0, 0};
  const float xc2[4] = {0.5f, 1.5f, 1.5f, 0.5f};
#pragma unroll
  for (int ky = 0; ky < 4; ++ky) {
    int yy = y - 2 + ky;
    if (yy < 0 || yy >= H) continue;
#pragma unroll
    for (int kx = 0; kx < 4; ++kx) {
      int xs = xx - 2 + kx;
      if (xs < 0 || xs >= W) continue;
      float w = xc2[ky] * xc2[kx] * 0.25f;
      const float4* s4 = (const float4*)(ang + ((size_t)(b * H + yy) * W + xs) * 8);
      float4 v0 = s4[0], v1 = s4[1];
      a0.x += w * v0.x; a0.y += w * v0.y; a0.z += w * v0.z; a0.w += w * v0.w;
      a1.x += w * v1.x; a1.y += w * v1.y; a1.z += w * v1.z; a1.w += w * v1.w;
    }
  }
  float4* o4 = (float4*)(pooled + (size_t)p * 8);
  o4[0] = a0; o4[1] = a1;
}

// ---------------------------------------------------------------- SIFT stage 3
// one wave per pixel; lane l handles channels 2l, 2l+1 (c = a*16 + (dy*4+dx))
__global__ void k_sift_desc(const float* __restrict__ pooled, unsigned short* __restrict__ spad) {
  constexpr int PH = H + 1, PW = W + 1;
  int tid = threadIdx.x;
  int wv = tid >> 6, lane = tid & 63;
  int p = blockIdx.x * 4 + wv;
  int b = p / HW, r = p % HW, yy = r / W, xx = r % W;
  int a = lane >> 3, jj = lane & 7;
  int j0 = jj * 2;
  int dy = j0 >> 2, dx = j0 & 3;
  int rr = yy + dy - 1;
  int c0 = xx + dx - 1, c1 = c0 + 1;
  bool rv = (rr >= 0 && rr <= H);
  int rc = min(max(rr, 0), H);
  const float* pb = pooled + ((size_t)(b * PH + rc) * PW) * 8 + a;
  float v0 = 0.0f, v1 = 0.0f;
  if (rv && c0 >= 0 && c0 <= W) v0 = pb[(size_t)c0 * 8];
  if (rv && c1 >= 0 && c1 <= W) v1 = pb[(size_t)c1 * 8];

  float n2 = v0 * v0 + v1 * v1;
#pragma unroll
  for (int m = 1; m < 64; m <<= 1) n2 += __shfl_xor(n2, m);
  float inv = 1.0f / fmaxf(sqrtf(n2), 1e-12f);
  v0 = fminf(v0 * inv, 0.2f);
  v1 = fminf(v1 * inv, 0.2f);
  float n2b = v0 * v0 + v1 * v1;
#pragma unroll
  for (int m = 1; m < 64; m <<= 1) n2b += __shfl_xor(n2b, m);
  inv = 1.0f / fmaxf(sqrtf(n2b), 1e-12f);
  v0 *= inv; v1 *= inv;
  float l1 = v0 + v1;
#pragma unroll
  for (int m = 1; m < 64; m <<= 1) l1 += __shfl_xor(l1, m);
  float il1 = 1.0f / fmaxf(l1, 1e-12f);
  v0 = sqrtf(v0 * il1 + 1e-10f);
  v1 = sqrtf(v1 * il1 + 1e-10f);
  unsigned int pk = (unsigned int)f2bf(v0) | ((unsigned int)f2bf(v1) << 16);
  *(unsigned int*)(spad + ((size_t)(b * IH5 + yy + 2) * P5 + xx + 2) * 128 + lane * 2) = pk;
}

// ---------------------------------------------------------------- weight prep: [t][co][ci] bf16
template <int CIN, int COUT, int KS>
__global__ void k_prep(const float* __restrict__ w, unsigned short* __restrict__ wbuf) {
  int i = blockIdx.x * 256 + threadIdx.x;
  if (i >= KS * KS * COUT * CIN) return;
  int t = i / (COUT * CIN), r2 = i % (COUT * CIN), co = r2 / CIN, e = r2 % CIN;
  wbuf[i] = f2bf(w[(co * CIN + e) * (KS * KS) + t]);
}

// ---------------------------------------------------------------- MFMA implicit-GEMM conv
// NHWC padded input, 128-px strip per block, all COUT channels, bf16 in / f32 acc.
// Block remap: xcd = bid&7 owns one xt strip + contiguous by-band -> tap re-reads are L2 hits.
template <int CIN, int COUT, int KS, int NG, int PADOFF>
__launch_bounds__(256)
__global__ void k_conv_mfma(const unsigned short* __restrict__ in, int IHt, int ipitch,
                            const unsigned short* __restrict__ wbuf,
                            const float* __restrict__ bias,
                            unsigned short* __restrict__ outraw,
                            float* __restrict__ part) {
  constexpr int BM = 128;
  constexpr int R = CIN * 2;          // bytes per row (pixel/co) in LDS
  constexpr int SA = BM * R;
  constexpr int SW = COUT * R;
  constexpr int KSTEPS = CIN / 32;
  constexpr int NF = COUT / 16;
  constexpr int SWZM = (R / 16) >= 8 ? 7 : (R / 16) - 1;
  constexpr int NIA = SA / 4096;
  constexpr int NIW = (SW + 4095) / 4096;
  __shared__ __align__(16) unsigned char smem[SA + SW];
  __shared__ float red[4][16];

  int tid = threadIdx.x;
  int lane = tid & 63, wv = tid >> 6;
  int l15 = lane & 15, hi = lane >> 4;
  int bid = blockIdx.x;
  // XCD-band remap: bits[2:1]->xt strip, bit0 -> by half, bid>>3 -> row within half
  int nby = gridDim.x >> 2;           // nb * H
  int xt = (bid >> 1) & 3;
  int by = (bid & 1) * (nby >> 1) + (bid >> 3);
  int y = by % H, b = by / H;
  int x0 = xt * BM;
  int slot = by * 4 + xt;             // logical slot for GN partials (sample-major)

  f32x4 acc[2][NF] = {};
  uint4 rA[NIA], rW[NIW];

  auto load_tap = [&](int t) {
    int ky = t / KS, kx = t % KS;
    const char* src = (const char*)(in + ((size_t)(b * IHt + y + ky + PADOFF) * ipitch + (x0 + kx + PADOFF)) * CIN);
    const char* wsrc = (const char*)(wbuf + (size_t)t * (SW / 2));
#pragma unroll
    for (int i = 0; i < NIA; ++i)
      rA[i] = *(const uint4*)(src + tid * 16 + i * 4096);
#pragma unroll
    for (int i = 0; i < NIW; ++i) {
      int d = tid * 16 + i * 4096;
      if ((SW & 4095) == 0 || d < SW) rW[i] = *(const uint4*)(wsrc + d);
    }
  };

  load_tap(0);
#pragma unroll 1
  for (int t = 0; t < KS * KS; ++t) {
    __syncthreads();   // previous tap's LDS reads complete
#pragma unroll
    for (int i = 0; i < NIA; ++i) {
      int d = tid * 16 + i * 4096;
      int px = d / R, q = d & (R - 1);
      *(uint4*)(smem + px * R + (q ^ ((px & SWZM) << 4))) = rA[i];
    }
#pragma unroll
    for (int i = 0; i < NIW; ++i) {
      int d = tid * 16 + i * 4096;
      if ((SW & 4095) == 0 || d < SW) {
        int co = d / R, q = d & (R - 1);
        *(uint4*)(smem + SA + co * R + (q ^ ((co & SWZM) << 4))) = rW[i];
      }
    }
    __syncthreads();
    if (t + 1 < KS * KS) load_tap(t + 1);   // prefetch next tap under compute
#pragma unroll
    for (int ks = 0; ks < KSTEPS; ++ks) {
      int koff = ks * 64 + hi * 16;
      bf16x8 af[2], bq[NF];
#pragma unroll
      for (int mi = 0; mi < 2; ++mi) {
        int px = wv * 32 + mi * 16 + l15;
        af[mi] = *(const bf16x8*)(smem + px * R + (koff ^ ((px & SWZM) << 4)));
      }
#pragma unroll
      for (int ni = 0; ni < NF; ++ni) {
        int co = ni * 16 + l15;
        bq[ni] = *(const bf16x8*)(smem + SA + co * R + (koff ^ ((co & SWZM) << 4)));
      }
#pragma unroll
      for (int mi = 0; mi < 2; ++mi)
#pragma unroll
        for (int ni = 0; ni < NF; ++ni)
          acc[mi][ni] = __builtin_amdgcn_mfma_f32_16x16x32_bf16(af[mi], bq[ni], acc[mi][ni], 0, 0, 0);
    }
  }

  // bias
#pragma unroll
  for (int ni = 0; ni < NF; ++ni) {
    float bv = bias[ni * 16 + l15];
#pragma unroll
    for (int mi = 0; mi < 2; ++mi)
#pragma unroll
      for (int rr = 0; rr < 4; ++rr)
        acc[mi][ni][rr] += bv;
  }
  // store raw NHWC bf16
  unsigned short* op = outraw + ((size_t)(b * H + y) * W + x0) * COUT;
#pragma unroll
  for (int mi = 0; mi < 2; ++mi)
#pragma unroll
    for (int rr = 0; rr < 4; ++rr) {
      int px = wv * 32 + mi * 16 + hi * 4 + rr;
#pragma unroll
      for (int ni = 0; ni < NF; ++ni)
        op[(size_t)px * COUT + ni * 16 + l15] = f2bf(acc[mi][ni][rr]);
    }
  // deterministic per-block GN partials (indexed by logical slot, not bid)
  if constexpr (NG > 0) {
    constexpr int GPC = COUT / NG;
#pragma unroll
    for (int ni = 0; ni < NF; ++ni) {
      float s = 0.0f, q = 0.0f;
#pragma unroll
      for (int mi = 0; mi < 2; ++mi)
#pragma unroll
        for (int rr = 0; rr < 4; ++rr) {
          float v = acc[mi][ni][rr];
          s += v; q += v * v;
        }
      s += __shfl_xor(s, 16); q += __shfl_xor(q, 16);
      s += __shfl_xor(s, 32); q += __shfl_xor(q, 32);
#pragma unroll
      for (int m = 1; m < GPC; m <<= 1) { s += __shfl_xor(s, m); q += __shfl_xor(q, m); }
      if (hi == 0 && (l15 % GPC) == 0) {
        int g = ni * (16 / GPC) + l15 / GPC;
        red[wv][g] = s;
        red[wv][NG + g] = q;
      }
    }
    __syncthreads();
    if (tid < 2 * NG)
      part[(size_t)slot * (2 * NG) + tid] =
          red[0][tid] + red[1][tid] + red[2][tid] + red[3][tid];
  }
}

// ---------------------------------------------------------------- GN finalize
template <int COUT, int NG>
__global__ void k_gn_fin(const float* __restrict__ part, int NB,
                         const float* __restrict__ gw, const float* __restrict__ gb,
                         float* __restrict__ scale, float* __restrict__ shift, float invN) {
  constexpr int GPC = COUT / NG;
  int b = blockIdx.x / NG, g = blockIdx.x % NG;
  int lane = threadIdx.x;
  float s = 0.0f, q = 0.0f;
  for (int i = lane; i < NB; i += 64) {
    const float* pp = part + (size_t)(b * NB + i) * (2 * NG);
    s += pp[g]; q += pp[NG + g];
  }
#pragma unroll
  for (int m = 1; m < 64; m <<= 1) { s += __shfl_xor(s, m); q += __shfl_xor(q, m); }
  if (lane == 0) {
    float mean = s * invN;
    float var = q * invN - mean * mean;
    float rstd = rsqrtf(var + 1e-5f);
#pragma unroll
    for (int j = 0; j < GPC; ++j) {
      int c = g * GPC + j;
      float sc = gw[c] * rstd;
      scale[b * COUT + c] = sc;
      shift[b * COUT + c] = gb[c] - mean * sc;
    }
  }
}

// ---------------------------------------------------------------- GN-apply (+ReLU, +skip) into padded buffer
template <int C, bool ADDSKIP>
__global__ void k_norm(const unsigned short* __restrict__ raw,
                       const unsigned short* __restrict__ skip,
                       const float* __restrict__ scale, const float* __restrict__ shift,
                       unsigned short* __restrict__ outpad) {
  int e = blockIdx.x * 256 + threadIdx.x;
  int idx = e * 8;
  int p = idx / C, c0 = idx % C;
  int b = p / HW, r = p % HW, y = r / W, xx = r % W;
  U8 v; v.q = *(const uint4*)(raw + (size_t)p * C + c0);
  U8 sk;
  if (ADDSKIP) sk.q = *(const uint4*)(skip + (size_t)p * C + c0);
  const float* sc = scale + b * C + c0;
  const float* sh = shift + b * C + c0;
  U8 o;
#pragma unroll
  for (int j = 0; j < 8; ++j) {
    float f = fmaxf(bf2f(v.u[j]) * sc[j] + sh[j], 0.0f);
    if (ADDSKIP) f += bf2f(sk.u[j]);
    o.u[j] = f2bf(f);
  }
  *(uint4*)(outpad + ((size_t)(b * IH3 + y + 1) * P3 + xx + 1) * C + c0) = o.q;
}

// ---------------------------------------------------------------- conv4 direct (16->8, 3x3) + GN partials
__global__ void k_conv4(const unsigned short* __restrict__ h3pad, const float* __restrict__ w4,
                        const float* __restrict__ b4, unsigned short* __restrict__ h4raw,
                        float* __restrict__ part) {
  __shared__ float wl[1152];
  __shared__ float red[4][8];
  for (int i = threadIdx.x; i < 1152; i += 256) {
    int t = i / 128, r2 = i % 128, ci = r2 >> 3, co = r2 & 7;
    wl[i] = w4[(co * 16 + ci) * 9 + t];
  }
  __syncthreads();
  int p = blockIdx.x * 256 + threadIdx.x;
  int b = p / HW, r = p % HW, y = r / W, xx = r % W;
  float acc[8];
#pragma unroll
  for (int co = 0; co < 8; ++co) acc[co] = b4[co];
#pragma unroll
  for (int t = 0; t < 9; ++t) {
    int ky = t / 3, kx = t % 3;
    const unsigned short* ip = h3pad + ((size_t)(b * IH3 + y + ky) * P3 + (xx + kx)) * 16;
    U8 u0, u1;
    u0.q = *(const uint4*)ip;
    u1.q = *(const uint4*)(ip + 8);
#pragma unroll
    for (int ci = 0; ci < 16; ++ci) {
      float iv = bf2f(ci < 8 ? u0.u[ci] : u1.u[ci - 8]);
#pragma unroll
      for (int co = 0; co < 8; ++co)
        acc[co] += iv * wl[t * 128 + ci * 8 + co];
    }
  }
  int lane = threadIdx.x & 63, wv = threadIdx.x >> 6;
  float s[4], q[4];
#pragma unroll
  for (int g = 0; g < 4; ++g) {
    s[g] = acc[2 * g] + acc[2 * g + 1];
    q[g] = acc[2 * g] * acc[2 * g] + acc[2 * g + 1] * acc[2 * g + 1];
  }
#pragma unroll
  for (int m = 1; m < 64; m <<= 1) {
#pragma unroll
    for (int g = 0; g < 4; ++g) { s[g] += __shfl_xor(s[g], m); q[g] += __shfl_xor(q[g], m); }
  }
  if (lane == 0) {
#pragma unroll
    for (int g = 0; g < 4; ++g) { red[wv][g] = s[g]; red[wv][4 + g] = q[g]; }
  }
  __syncthreads();
  if (threadIdx.x < 8)
    part[(size_t)blockIdx.x * 8 + threadIdx.x] =
        red[0][threadIdx.x] + red[1][threadIdx.x] + red[2][threadIdx.x] + red[3][threadIdx.x];
  U8 o;
#pragma unroll
  for (int co = 0; co < 8; ++co) o.u[co] = f2bf(acc[co]);
  *(uint4*)(h4raw + (size_t)p * 8) = o.q;
}

// ---------------------------------------------------------------- norm4 + skip2 (1x1 32->8) fused
__global__ void k_norm4(const unsigned short* __restrict__ h4raw, const unsigned short* __restrict__ blkpad,
                        const float* __restrict__ scale, const float* __restrict__ shift,
                        const float* __restrict__ sw2, const float* __restrict__ sb2,
                        unsigned short* __restrict__ blk2pad) {
  __shared__ float wl[256];
  {
    int i = threadIdx.x;
    int ci = i >> 3, co = i & 7;
    wl[i] = sw2[co * 32 + ci];
  }
  __syncthreads();
  int p = blockIdx.x * 256 + threadIdx.x;
  int b = p / HW, r = p % HW, y = r / W, xx = r % W;
  float acc[8];
#pragma unroll
  for (int co = 0; co < 8; ++co) acc[co] = sb2[co];
  size_t cbase = ((size_t)(b * IH3 + y + 1) * P3 + (xx + 1));
  const unsigned short* bp = blkpad + cbase * 32;
#pragma unroll
  for (int half = 0; half < 4; ++half) {
    U8 u; u.q = *(const uint4*)(bp + half * 8);
#pragma unroll
    for (int j = 0; j < 8; ++j) {
      float iv = bf2f(u.u[j]);
      int ci = half * 8 + j;
#pragma unroll
      for (int co = 0; co < 8; ++co) acc[co] += iv * wl[ci * 8 + co];
    }
  }
  U8 hv; hv.q = *(const uint4*)(h4raw + (size_t)p * 8);
  U8 o;
#pragma unroll
  for (int co = 0; co < 8; ++co) {
    float f = fmaxf(bf2f(hv.u[co]) * scale[b * 8 + co] + shift[b * 8 + co], 0.0f) + acc[co];
    o.u[co] = f2bf(f);
  }
  *(uint4*)(blk2pad + cbase * 8) = o.q;
}

// ---------------------------------------------------------------- conv5 direct (8->2, 3x3)
__global__ void k_conv5(const unsigned short* __restrict__ blk2pad, const float* __restrict__ w5,
                        const float* __restrict__ b5, float* __restrict__ h5) {
  __shared__ float wl[144];
  if (threadIdx.x < 144) {
    int i = threadIdx.x;
    int t = i / 16, r2 = i % 16, ci = r2 >> 1, co = r2 & 1;
    wl[i] = w5[(co * 8 + ci) * 9 + t];
  }
  __syncthreads();
  int p = blockIdx.x * 256 + threadIdx.x;
  int b = p / HW, r = p % HW, y = r / W, xx = r % W;
  float a0 = b5[0], a1 = b5[1];
#pragma unroll
  for (int t = 0; t < 9; ++t) {
    int ky = t / 3, kx = t % 3;
    const unsigned short* ip = blk2pad + ((size_t)(b * IH3 + y + ky) * P3 + (xx + kx)) * 8;
    U8 u; u.q = *(const uint4*)ip;
#pragma unroll
    for (int ci = 0; ci < 8; ++ci) {
      float iv = bf2f(u.u[ci]);
      a0 += iv * wl[t * 16 + ci * 2];
      a1 += iv * wl[t * 16 + ci * 2 + 1];
    }
  }
  h5[(size_t)p * 2] = a0;
  h5[(size_t)p * 2 + 1] = a1;
}

// ---------------------------------------------------------------- joint bilateral + tanh + scale
__global__ void k_bilateral(const float* __restrict__ h5, const float* __restrict__ x,
                            float* __restrict__ out, int nTot) {
  int p = blockIdx.x * 256 + threadIdx.x;
  if (p >= nTot) return;
  int b = p / HW, r = p % HW, y = r / W, xx = r % W;
  const float* xb = x + (size_t)b * HW;
  float xc = xb[r];
  float e1 = expf(-1.0f / 4.5f), e0 = expf(-4.0f / 4.5f);
  float gs = 1.0f + 2.0f * e1 + 2.0f * e0;
  float g[5] = {e0 / gs, e1 / gs, 1.0f / gs, e1 / gs, e0 / gs};
  float n0 = 0.0f, n1 = 0.0f, den = 0.0f;
#pragma unroll
  for (int dy = 0; dy < 5; ++dy) {
    int yn = y + dy - 2;
    yn = yn < 0 ? -yn : (yn >= H ? 2 * H - 2 - yn : yn);
#pragma unroll
    for (int dx = 0; dx < 5; ++dx) {
      int xn = xx + dx - 2;
      xn = xn < 0 ? -xn : (xn >= W ? 2 * W - 2 - xn : xn);
      float xv = xb[yn * W + xn];
      float d = xv - xc;
      float wgt = g[dy] * g[dx] * expf(-200.0f * d * d);
      den += wgt;
      const float* hp = h5 + ((size_t)(b * HW) + yn * W + xn) * 2;
      n0 += wgt * hp[0];
      n1 += wgt * hp[1];
    }
  }
  float o0 = tanhf(n0 / den) * 0.436f;
  float o1 = tanhf(n1 / den) * 0.615f;
  out[(size_t)(b * 2) * HW + r] = o0;
  out[(size_t)(b * 2 + 1) * HW + r] = o1;
}

// ---------------------------------------------------------------- host
extern "C" void kernel_launch(void* const* d_in, const int* in_sizes, int n_in,
                              void* d_out, int out_size, void* d_ws, size_t ws_size,
                              hipStream_t stream) {
  (void)in_sizes; (void)n_in; (void)out_size;
  const float* x   = (const float*)d_in[0];
  const float* w1  = (const float*)d_in[1];
  const float* b1  = (const float*)d_in[2];
  const float* g1w = (const float*)d_in[3];
  const float* g1b = (const float*)d_in[4];
  const float* w2  = (const float*)d_in[5];
  const float* b2  = (const float*)d_in[6];
  const float* g2w = (const float*)d_in[7];
  const float* g2b = (const float*)d_in[8];
  const float* w3  = (const float*)d_in[9];
  const float* b3  = (const float*)d_in[10];
  const float* g3w = (const float*)d_in[11];
  const float* g3b = (const float*)d_in[12];
  const float* w4  = (const float*)d_in[13];
  const float* b4  = (const float*)d_in[14];
  const float* g4w = (const float*)d_in[15];
  const float* g4b = (const float*)d_in[16];
  const float* w5  = (const float*)d_in[17];
  const float* b5  = (const float*)d_in[18];
  const float* sw1 = (const float*)d_in[19];
  const float* sb1 = (const float*)d_in[20];
  const float* sw2 = (const float*)d_in[21];
  const float* sb2 = (const float*)d_in[22];
  float* out = (float*)d_out;
  char* ws = (char*)d_ws;

  auto AL = [](size_t v) { return (v + 255) & ~(size_t)255; };
  // per-sample byte strides
  const size_t sSPAD  = (size_t)IH5 * P5 * 128 * 2;
  const size_t sANG   = (size_t)HW * 8 * 4;
  const size_t sH1RAW = (size_t)HW * 64 * 2;
  const size_t sH1PAD = (size_t)IH3 * P3 * 64 * 2;
  const size_t sH2RAW = (size_t)HW * 32 * 2;
  const size_t sBLKP  = (size_t)IH3 * P3 * 32 * 2;
  const size_t sH3RAW = (size_t)HW * 16 * 2;
  const size_t sH3PAD = (size_t)IH3 * P3 * 16 * 2;
  const size_t sH4RAW = (size_t)HW * 8 * 2;
  const size_t sBLK2  = (size_t)IH3 * P3 * 8 * 2;

  // choose largest batch-chunk that fits the workspace
  int nb = 0;
  size_t offB = 0, offH1PAD = 0, offSmall = 0;
  for (int cand = 4; cand >= 1; cand >>= 1) {
    size_t oB   = AL((size_t)cand * sSPAD);
    size_t oH1P = AL(oB + (size_t)cand * sH1RAW);
    size_t oS   = AL(oH1P + (size_t)cand * sH1PAD);
    size_t need = oS + AL(512 * 1024)                 // wb1..wbs1
                     + AL((size_t)4 * 1080 * 16 * 4)  // partials (max)
                     + 4 * 4096;                      // scale/shift slots
    if (ws_size >= need) { nb = cand; offB = oB; offH1PAD = oH1P; offSmall = oS; break; }
  }
  if (nb == 0) {  // diagnostic: workspace too small even for 1-sample chunks
    k_fill<<<(BN * 2 * HW + 255) / 256, 256, 0, stream>>>(out, BN * 2 * HW, 123.0f);
    return;
  }

  // small-region carve
  size_t oWB1  = offSmall;
  size_t oWB2  = AL(oWB1 + 25 * 64 * 128 * 2);
  size_t oWB3  = AL(oWB2 + 9 * 32 * 64 * 2);
  size_t oWBS  = AL(oWB3 + 9 * 16 * 32 * 2);
  size_t oPART = AL(oWBS + 32 * 128 * 2);
  size_t oSC1  = AL(oPART + (size_t)4 * 1080 * 16 * 4);
  size_t oSC2  = oSC1 + 4096, oSC3 = oSC2 + 4096, oSC4 = oSC3 + 4096;

  unsigned short* wb1  = (unsigned short*)(ws + oWB1);
  unsigned short* wb2  = (unsigned short*)(ws + oWB2);
  unsigned short* wb3  = (unsigned short*)(ws + oWB3);
  unsigned short* wbs1 = (unsigned short*)(ws + oWBS);
  float* part = (float*)(ws + oPART);
  float* sc1 = (float*)(ws + oSC1); float* sh1 = sc1 + nb * 64;
  float* sc2 = (float*)(ws + oSC2); float* sh2 = sc2 + nb * 32;
  float* sc3 = (float*)(ws + oSC3); float* sh3 = sc3 + nb * 16;
  float* sc4 = (float*)(ws + oSC4); float* sh4 = sc4 + nb * 8;

  k_prep<128, 64, 5><<<800, 256, 0, stream>>>(w1, wb1);
  k_prep<64, 32, 3><<<72, 256, 0, stream>>>(w2, wb2);
  k_prep<32, 16, 3><<<18, 256, 0, stream>>>(w3, wb3);
  k_prep<128, 32, 1><<<16, 256, 0, stream>>>(sw1, wbs1);

  // tail-region offsets inside the (dead-after-skip1) spad region
  size_t t0 = AL((size_t)nb * sBLKP);             // h3raw
  size_t t1 = AL(t0 + (size_t)nb * sH3RAW);       // h3pad
  size_t t2 = AL(t1 + (size_t)nb * sH3PAD);       // h4raw
  size_t t3 = AL(t2 + (size_t)nb * sH4RAW);       // blk2pad
  size_t t4 = AL(t3 + (size_t)nb * sBLK2);        // h5

  for (int b0 = 0; b0 < BN; b0 += nb) {
    const float* x_c = x + (size_t)b0 * HW;
    float* out_c = out + (size_t)b0 * 2 * HW;
    unsigned short* spad   = (unsigned short*)(ws);
    float*          ang    = (float*)(ws + offB);
    float*          pooled = (float*)(ws + AL(offB + (size_t)nb * sANG));
    unsigned short* h1raw  = (unsigned short*)(ws + offB);
    unsigned short* h1pad  = (unsigned short*)(ws + offH1PAD);
    unsigned short* h2raw  = (unsigned short*)(ws + offB);
    unsigned short* sk1    = (unsigned short*)(ws + offB + (size_t)nb * sH2RAW);
    unsigned short* blkpad = (unsigned short*)(ws);
    unsigned short* h3raw  = (unsigned short*)(ws + t0);
    unsigned short* h3pad  = (unsigned short*)(ws + t1);
    unsigned short* h4raw  = (unsigned short*)(ws + t2);
    unsigned short* blk2   = (unsigned short*)(ws + t3);
    float*          h5     = (float*)(ws + t4);
    int nHW = nb * HW;

    hipMemsetAsync(spad, 0, (size_t)nb * sSPAD, stream);
    hipMemsetAsync(h1pad, 0, (size_t)nb * sH1PAD, stream);

    k_sift_ang<<<nb * 540, 256, 0, stream>>>(x_c, ang, nHW);
    int nPP = nb * (H + 1) * (W + 1);
    k_sift_pool<<<(nPP + 255) / 256, 256, 0, stream>>>(ang, pooled, nPP);
    k_sift_desc<<<nHW / 4, 256, 0, stream>>>(pooled, spad);

    k_conv_mfma<128, 64, 5, 8, 0><<<nb * 1080, 256, 0, stream>>>(spad, IH5, P5, wb1, b1, h1raw, part);
    k_gn_fin<64, 8><<<nb * 8, 64, 0, stream>>>(part, 1080, g1w, g1b, sc1, sh1, 1.0f / (8.0f * HW));
    k_norm<64, false><<<nb * 4320, 256, 0, stream>>>(h1raw, nullptr, sc1, sh1, h1pad);

    k_conv_mfma<64, 32, 3, 8, 0><<<nb * 1080, 256, 0, stream>>>(h1pad, IH3, P3, wb2, b2, h2raw, part);
    k_gn_fin<32, 8><<<nb * 8, 64, 0, stream>>>(part, 1080, g2w, g2b, sc2, sh2, 1.0f / (4.0f * HW));
    k_conv_mfma<128, 32, 1, 0, 2><<<nb * 1080, 256, 0, stream>>>(spad, IH5, P5, wbs1, sb1, sk1, nullptr);

    // spad is dead now; its region hosts blkpad + tail buffers
    hipMemsetAsync(blkpad, 0, (size_t)nb * sBLKP, stream);
    hipMemsetAsync(h3pad, 0, (size_t)nb * sH3PAD, stream);
    hipMemsetAsync(blk2, 0, (size_t)nb * sBLK2, stream);

    k_norm<32, true><<<nb * 2160, 256, 0, stream>>>(h2raw, sk1, sc2, sh2, blkpad);

    k_conv_mfma<32, 16, 3, 4, 0><<<nb * 1080, 256, 0, stream>>>(blkpad, IH3, P3, wb3, b3, h3raw, part);
    k_gn_fin<16, 4><<<nb * 4, 64, 0, stream>>>(part, 1080, g3w, g3b, sc3, sh3, 1.0f / (4.0f * HW));
    k_norm<16, false><<<nb * 1080, 256, 0, stream>>>(h3raw, nullptr, sc3, sh3, h3pad);

    k_conv4<<<nb * 540, 256, 0, stream>>>(h3pad, w4, b4, h4raw, part);
    k_gn_fin<8, 4><<<nb * 4, 64, 0, stream>>>(part, 540, g4w, g4b, sc4, sh4, 1.0f / (2.0f * HW));
    k_norm4<<<nb * 540, 256, 0, stream>>>(h4raw, blkpad, sc4, sh4, sw2, sb2, blk2);

    k_conv5<<<nb * 540, 256, 0, stream>>>(blk2, w5, b5, h5);
    k_bilateral<<<nb * 540, 256, 0, stream>>>(h5, x_c, out_c, nHW);
  }
}

// Round 4
// 827.020 us; speedup vs baseline: 2.8150x; 2.7337x over previous
//
#include <hip/hip_runtime.h>

#define DEV __device__ __forceinline__

typedef __bf16 bf16x8 __attribute__((ext_vector_type(8)));
typedef float f32x4 __attribute__((ext_vector_type(4)));

union U8 { uint4 q; unsigned short u[8]; };

constexpr int BN = 4, H = 270, W = 512, HW = H * W;
constexpr int IH5 = 274, P5 = 516;   // pad-2 buffers (SIFT descriptor)
constexpr int IH3 = 272, P3 = 514;   // pad-1 buffers

DEV unsigned short f2bf(float f) {
  unsigned int u = __builtin_bit_cast(unsigned int, f);
  u = (u + 0x7FFFu + ((u >> 16) & 1u)) >> 16;
  return (unsigned short)u;
}
DEV float bf2f(unsigned short h) {
  return __builtin_bit_cast(float, (unsigned int)h << 16);
}

#define GLL16(g, l)                                                                        \
  __builtin_amdgcn_global_load_lds((const __attribute__((address_space(1))) void*)(g),     \
                                   (__attribute__((address_space(3))) void*)(l), 16, 0, 0)

// ---------------------------------------------------------------- diagnostic
__global__ void k_fill(float* __restrict__ out, int n, float v) {
  int i = blockIdx.x * 256 + threadIdx.x;
  if (i < n) out[i] = v;
}

// ---------------------------------------------------------------- SIFT stage 1
__global__ void k_sift_ang(const float* __restrict__ x, float* __restrict__ ang, int nTot) {
  int p = blockIdx.x * 256 + threadIdx.x;
  if (p >= nTot) return;
  int b = p / HW, r = p % HW, y = r / W, xx = r % W;
  const float* xb = x + (size_t)b * HW;
  float xm = xb[y * W + (xx > 0 ? xx - 1 : 0)];
  float xp = xb[y * W + (xx < W - 1 ? xx + 1 : W - 1)];
  float ym = xb[(y > 0 ? y - 1 : 0) * W + xx];
  float yp = xb[(y < H - 1 ? y + 1 : H - 1) * W + xx];
  float gx = (xp - xm) * 0.5f, gy = (yp - ym) * 0.5f;
  float mag = sqrtf(gx * gx + gy * gy + 1e-10f);
  float ori = atan2f(gy, gx + 1e-10f) + 6.2831855f;
  float o = (8.0f * ori) / 6.2831855f;
  float bo0f = floorf(o);
  float wo1 = o - bo0f;
  int b0 = ((int)bo0f) & 7;
  int b1 = (b0 + 1) & 7;
  float w0m = (1.0f - wo1) * mag, w1m = wo1 * mag;
  float v[8];
#pragma unroll
  for (int k = 0; k < 8; ++k)
    v[k] = (k == b0 ? w0m : 0.0f) + (k == b1 ? w1m : 0.0f);
  float4* o4 = (float4*)(ang + (size_t)p * 8);
  o4[0] = make_float4(v[0], v[1], v[2], v[3]);
  o4[1] = make_float4(v[4], v[5], v[6], v[7]);
}

// ---------------------------------------------------------------- SIFT stage 2
__global__ void k_sift_pool(const float* __restrict__ ang, float* __restrict__ pooled, int nTot) {
  constexpr int PH = H + 1, PW = W + 1;
  int p = blockIdx.x * 256 + threadIdx.x;
  if (p >= nTot) return;
  int b = p / (PH * PW), r = p % (PH * PW), y = r / PW, xx = r % PW;
  float4 a0 = {0, 0, 0, 0}, a1 = {0, 0, 0, 0};
  const float xc2[4] = {0.5f, 1.5f, 1.5f, 0.5f};
#pragma unroll
  for (int ky = 0; ky < 4; ++ky) {
    int yy = y - 2 + ky;
    if (yy < 0 || yy >= H) continue;
#pragma unroll
    for (int kx = 0; kx < 4; ++kx) {
      int xs = xx - 2 + kx;
      if (xs < 0 || xs >= W) continue;
      float w = xc2[ky] * xc2[kx] * 0.25f;
      const float4* s4 = (const float4*)(ang + ((size_t)(b * H + yy) * W + xs) * 8);
      float4 v0 = s4[0], v1 = s4[1];
      a0.x += w * v0.x; a0.y += w * v0.y; a0.z += w * v0.z; a0.w += w * v0.w;
      a1.x += w * v1.x; a1.y += w * v1.y; a1.z += w * v1.z; a1.w += w * v1.w;
    }
  }
  float4* o4 = (float4*)(pooled + (size_t)p * 8);
  o4[0] = a0; o4[1] = a1;
}

// ---------------------------------------------------------------- SIFT stage 3
__global__ void k_sift_desc(const float* __restrict__ pooled, unsigned short* __restrict__ spad) {
  constexpr int PH = H + 1, PW = W + 1;
  int tid = threadIdx.x;
  int wv = tid >> 6, lane = tid & 63;
  int p = blockIdx.x * 4 + wv;
  int b = p / HW, r = p % HW, yy = r / W, xx = r % W;
  int a = lane >> 3, jj = lane & 7;
  int j0 = jj * 2;
  int dy = j0 >> 2, dx = j0 & 3;
  int rr = yy + dy - 1;
  int c0 = xx + dx - 1, c1 = c0 + 1;
  bool rv = (rr >= 0 && rr <= H);
  int rc = min(max(rr, 0), H);
  const float* pb = pooled + ((size_t)(b * PH + rc) * PW) * 8 + a;
  float v0 = 0.0f, v1 = 0.0f;
  if (rv && c0 >= 0 && c0 <= W) v0 = pb[(size_t)c0 * 8];
  if (rv && c1 >= 0 && c1 <= W) v1 = pb[(size_t)c1 * 8];

  float n2 = v0 * v0 + v1 * v1;
#pragma unroll
  for (int m = 1; m < 64; m <<= 1) n2 += __shfl_xor(n2, m);
  float inv = 1.0f / fmaxf(sqrtf(n2), 1e-12f);
  v0 = fminf(v0 * inv, 0.2f);
  v1 = fminf(v1 * inv, 0.2f);
  float n2b = v0 * v0 + v1 * v1;
#pragma unroll
  for (int m = 1; m < 64; m <<= 1) n2b += __shfl_xor(n2b, m);
  inv = 1.0f / fmaxf(sqrtf(n2b), 1e-12f);
  v0 *= inv; v1 *= inv;
  float l1 = v0 + v1;
#pragma unroll
  for (int m = 1; m < 64; m <<= 1) l1 += __shfl_xor(l1, m);
  float il1 = 1.0f / fmaxf(l1, 1e-12f);
  v0 = sqrtf(v0 * il1 + 1e-10f);
  v1 = sqrtf(v1 * il1 + 1e-10f);
  unsigned int pk = (unsigned int)f2bf(v0) | ((unsigned int)f2bf(v1) << 16);
  *(unsigned int*)(spad + ((size_t)(b * IH5 + yy + 2) * P5 + xx + 2) * 128 + lane * 2) = pk;
}

// ---------------------------------------------------------------- weight prep: [t][co][ci] bf16
template <int CIN, int COUT, int KS>
__global__ void k_prep(const float* __restrict__ w, unsigned short* __restrict__ wbuf) {
  int i = blockIdx.x * 256 + threadIdx.x;
  if (i >= KS * KS * COUT * CIN) return;
  int t = i / (COUT * CIN), r2 = i % (COUT * CIN), co = r2 / CIN, e = r2 % CIN;
  wbuf[i] = f2bf(w[(co * CIN + e) * (KS * KS) + t]);
}

// ---------------------------------------------------------------- slab MFMA conv
// Row-slab staged once per ky via global_load_lds (pre-swizzled source, linear LDS);
// per-tap W double-buffered + prefetched under MFMA. Optional fused center-tap 1x1 skip.
template <int CIN, int COUT, int KS, int NG, bool FSKIP>
__launch_bounds__(256)
__global__ void k_conv_slab(const unsigned short* __restrict__ in, int IHt, int ipitch,
                            const unsigned short* __restrict__ wtap,
                            const float* __restrict__ bias,
                            const unsigned short* __restrict__ wsk,
                            const float* __restrict__ skb,
                            unsigned short* __restrict__ outraw,
                            unsigned short* __restrict__ skraw,
                            float* __restrict__ part) {
  constexpr int BM = 128;
  constexpr int R = CIN * 2;                 // bytes per pixel/co row
  constexpr int SLABPX = BM + KS - 1;
  constexpr int SLAB = SLABPX * R;
  constexpr int SW = COUT * R;               // one tap's weight slice
  constexpr int SSK = FSKIP ? 32 * R : 0;
  constexpr int KSTEPS = CIN / 32;
  constexpr int NF = COUT / 16;
  constexpr int SWZM = (R / 16) >= 8 ? 7 : (R / 16) - 1;
  __shared__ __align__(16) unsigned char smem[SLAB + 2 * SW + SSK + 16];
  __shared__ float red[4][16];

  int tid = threadIdx.x;
  int lane = tid & 63, wv = tid >> 6;
  int l15 = lane & 15, hi = lane >> 4;
  int bid = blockIdx.x;
  int nby = gridDim.x >> 2;
  int xt = (bid >> 1) & 3;
  int by = (bid & 1) * (nby >> 1) + (bid >> 3);
  int y = by % H, b = by / H;
  int x0 = xt * BM;
  int slot = by * 4 + xt;

  f32x4 acc[2][NF] = {};
  f32x4 ask[2][2] = {};

  auto stage_slab = [&](int ky) {
    const char* src = (const char*)(in + ((size_t)(b * IHt + y + ky) * ipitch + x0) * CIN);
    for (int d = tid * 16; d < SLAB; d += 4096) {
      int px = d / R, q = d % R;
      int g = px * R + (q ^ ((px & SWZM) << 4));
      GLL16(src + g, smem + d);
    }
  };
  auto stage_w = [&](int t, int pbuf) {
    const char* src = (const char*)(wtap + (size_t)t * (SW / 2));
    unsigned char* dst = smem + SLAB + pbuf * SW;
    for (int d = tid * 16; d < SW; d += 4096) {
      int co = d / R, q = d % R;
      int g = co * R + (q ^ ((co & SWZM) << 4));
      GLL16(src + g, dst + d);
    }
  };

  stage_slab(0);
  stage_w(0, 0);
  if constexpr (FSKIP) {
    const char* src = (const char*)wsk;
    unsigned char* dst = smem + SLAB + 2 * SW;
    for (int d = tid * 16; d < SSK; d += 4096) {
      int co = d / R, q = d % R;
      int g = co * R + (q ^ ((co & SWZM) << 4));
      GLL16(src + g, dst + d);
    }
  }
  __syncthreads();   // compiler drains vmcnt before barrier -> staged data visible

#pragma unroll 1
  for (int ky = 0; ky < KS; ++ky) {
#pragma unroll
    for (int kx = 0; kx < KS; ++kx) {
      int t = ky * KS + kx;
      if (t + 1 < KS * KS) stage_w(t + 1, (t + 1) & 1);   // prefetch under compute
      const unsigned char* wb = smem + SLAB + (t & 1) * SW;
      bool dsk = FSKIP && (ky == KS / 2) && (kx == KS / 2);
#pragma unroll
      for (int ks = 0; ks < KSTEPS; ++ks) {
        int koff = ks * 64 + hi * 16;
        bf16x8 af[2];
#pragma unroll
        for (int mi = 0; mi < 2; ++mi) {
          int px = wv * 32 + mi * 16 + l15 + kx;
          af[mi] = *(const bf16x8*)(smem + px * R + (koff ^ ((px & SWZM) << 4)));
        }
#pragma unroll
        for (int ni = 0; ni < NF; ++ni) {
          int co = ni * 16 + l15;
          bf16x8 bq = *(const bf16x8*)(wb + co * R + (koff ^ ((co & SWZM) << 4)));
#pragma unroll
          for (int mi = 0; mi < 2; ++mi)
            acc[mi][ni] = __builtin_amdgcn_mfma_f32_16x16x32_bf16(af[mi], bq, acc[mi][ni], 0, 0, 0);
        }
        if constexpr (FSKIP) {
          if (dsk) {
#pragma unroll
            for (int ni = 0; ni < 2; ++ni) {
              int co = ni * 16 + l15;
              bf16x8 bq = *(const bf16x8*)(smem + SLAB + 2 * SW + co * R + (koff ^ ((co & SWZM) << 4)));
#pragma unroll
              for (int mi = 0; mi < 2; ++mi)
                ask[mi][ni] = __builtin_amdgcn_mfma_f32_16x16x32_bf16(af[mi], bq, ask[mi][ni], 0, 0, 0);
            }
          }
        }
      }
      __syncthreads();   // drains W(t+1) prefetch; releases wbuf[(t+1)&1] for reuse
    }
    if (ky + 1 < KS) { stage_slab(ky + 1); __syncthreads(); }
  }

  // bias
#pragma unroll
  for (int ni = 0; ni < NF; ++ni) {
    float bv = bias[ni * 16 + l15];
#pragma unroll
    for (int mi = 0; mi < 2; ++mi)
#pragma unroll
      for (int rr = 0; rr < 4; ++rr)
        acc[mi][ni][rr] += bv;
  }
  // store raw NHWC bf16
  unsigned short* op = outraw + ((size_t)(b * H + y) * W + x0) * COUT;
#pragma unroll
  for (int mi = 0; mi < 2; ++mi)
#pragma unroll
    for (int rr = 0; rr < 4; ++rr) {
      int px = wv * 32 + mi * 16 + hi * 4 + rr;
#pragma unroll
      for (int ni = 0; ni < NF; ++ni)
        op[(size_t)px * COUT + ni * 16 + l15] = f2bf(acc[mi][ni][rr]);
    }
  // fused skip output
  if constexpr (FSKIP) {
#pragma unroll
    for (int ni = 0; ni < 2; ++ni) {
      float bv = skb[ni * 16 + l15];
#pragma unroll
      for (int mi = 0; mi < 2; ++mi)
#pragma unroll
        for (int rr = 0; rr < 4; ++rr)
          ask[mi][ni][rr] += bv;
    }
    unsigned short* ops = skraw + ((size_t)(b * H + y) * W + x0) * 32;
#pragma unroll
    for (int mi = 0; mi < 2; ++mi)
#pragma unroll
      for (int rr = 0; rr < 4; ++rr) {
        int px = wv * 32 + mi * 16 + hi * 4 + rr;
#pragma unroll
        for (int ni = 0; ni < 2; ++ni)
          ops[(size_t)px * 32 + ni * 16 + l15] = f2bf(ask[mi][ni][rr]);
      }
  }
  // deterministic per-block GN partials (logical slot indexing)
  if constexpr (NG > 0) {
    constexpr int GPC = COUT / NG;
#pragma unroll
    for (int ni = 0; ni < NF; ++ni) {
      float s = 0.0f, q = 0.0f;
#pragma unroll
      for (int mi = 0; mi < 2; ++mi)
#pragma unroll
        for (int rr = 0; rr < 4; ++rr) {
          float v = acc[mi][ni][rr];
          s += v; q += v * v;
        }
      s += __shfl_xor(s, 16); q += __shfl_xor(q, 16);
      s += __shfl_xor(s, 32); q += __shfl_xor(q, 32);
#pragma unroll
      for (int m = 1; m < GPC; m <<= 1) { s += __shfl_xor(s, m); q += __shfl_xor(q, m); }
      if (hi == 0 && (l15 % GPC) == 0) {
        int g = ni * (16 / GPC) + l15 / GPC;
        red[wv][g] = s;
        red[wv][NG + g] = q;
      }
    }
    __syncthreads();
    if (tid < 2 * NG)
      part[(size_t)slot * (2 * NG) + tid] =
          red[0][tid] + red[1][tid] + red[2][tid] + red[3][tid];
  }
}

// ---------------------------------------------------------------- GN finalize
template <int COUT, int NG>
__global__ void k_gn_fin(const float* __restrict__ part, int NB,
                         const float* __restrict__ gw, const float* __restrict__ gb,
                         float* __restrict__ scale, float* __restrict__ shift, float invN) {
  constexpr int GPC = COUT / NG;
  int b = blockIdx.x / NG, g = blockIdx.x % NG;
  int lane = threadIdx.x;
  float s = 0.0f, q = 0.0f;
  for (int i = lane; i < NB; i += 64) {
    const float* pp = part + (size_t)(b * NB + i) * (2 * NG);
    s += pp[g]; q += pp[NG + g];
  }
#pragma unroll
  for (int m = 1; m < 64; m <<= 1) { s += __shfl_xor(s, m); q += __shfl_xor(q, m); }
  if (lane == 0) {
    float mean = s * invN;
    float var = q * invN - mean * mean;
    float rstd = rsqrtf(var + 1e-5f);
#pragma unroll
    for (int j = 0; j < GPC; ++j) {
      int c = g * GPC + j;
      float sc = gw[c] * rstd;
      scale[b * COUT + c] = sc;
      shift[b * COUT + c] = gb[c] - mean * sc;
    }
  }
}

// ---------------------------------------------------------------- GN-apply (+ReLU, +skip)
template <int C, bool ADDSKIP>
__global__ void k_norm(const unsigned short* __restrict__ raw,
                       const unsigned short* __restrict__ skip,
                       const float* __restrict__ scale, const float* __restrict__ shift,
                       unsigned short* __restrict__ outpad) {
  int e = blockIdx.x * 256 + threadIdx.x;
  int idx = e * 8;
  int p = idx / C, c0 = idx % C;
  int b = p / HW, r = p % HW, y = r / W, xx = r % W;
  U8 v; v.q = *(const uint4*)(raw + (size_t)p * C + c0);
  U8 sk;
  if (ADDSKIP) sk.q = *(const uint4*)(skip + (size_t)p * C + c0);
  const float* sc = scale + b * C + c0;
  const float* sh = shift + b * C + c0;
  U8 o;
#pragma unroll
  for (int j = 0; j < 8; ++j) {
    float f = fmaxf(bf2f(v.u[j]) * sc[j] + sh[j], 0.0f);
    if (ADDSKIP) f += bf2f(sk.u[j]);
    o.u[j] = f2bf(f);
  }
  *(uint4*)(outpad + ((size_t)(b * IH3 + y + 1) * P3 + xx + 1) * C + c0) = o.q;
}

// ---------------------------------------------------------------- conv4 direct (16->8, 3x3)
__global__ void k_conv4(const unsigned short* __restrict__ h3pad, const float* __restrict__ w4,
                        const float* __restrict__ b4, unsigned short* __restrict__ h4raw,
                        float* __restrict__ part) {
  __shared__ float wl[1152];
  __shared__ float red[4][8];
  for (int i = threadIdx.x; i < 1152; i += 256) {
    int t = i / 128, r2 = i % 128, ci = r2 >> 3, co = r2 & 7;
    wl[i] = w4[(co * 16 + ci) * 9 + t];
  }
  __syncthreads();
  int p = blockIdx.x * 256 + threadIdx.x;
  int b = p / HW, r = p % HW, y = r / W, xx = r % W;
  float acc[8];
#pragma unroll
  for (int co = 0; co < 8; ++co) acc[co] = b4[co];
#pragma unroll
  for (int t = 0; t < 9; ++t) {
    int ky = t / 3, kx = t % 3;
    const unsigned short* ip = h3pad + ((size_t)(b * IH3 + y + ky) * P3 + (xx + kx)) * 16;
    U8 u0, u1;
    u0.q = *(const uint4*)ip;
    u1.q = *(const uint4*)(ip + 8);
#pragma unroll
    for (int ci = 0; ci < 16; ++ci) {
      float iv = bf2f(ci < 8 ? u0.u[ci] : u1.u[ci - 8]);
#pragma unroll
      for (int co = 0; co < 8; ++co)
        acc[co] += iv * wl[t * 128 + ci * 8 + co];
    }
  }
  int lane = threadIdx.x & 63, wv = threadIdx.x >> 6;
  float s[4], q[4];
#pragma unroll
  for (int g = 0; g < 4; ++g) {
    s[g] = acc[2 * g] + acc[2 * g + 1];
    q[g] = acc[2 * g] * acc[2 * g] + acc[2 * g + 1] * acc[2 * g + 1];
  }
#pragma unroll
  for (int m = 1; m < 64; m <<= 1) {
#pragma unroll
    for (int g = 0; g < 4; ++g) { s[g] += __shfl_xor(s[g], m); q[g] += __shfl_xor(q[g], m); }
  }
  if (lane == 0) {
#pragma unroll
    for (int g = 0; g < 4; ++g) { red[wv][g] = s[g]; red[wv][4 + g] = q[g]; }
  }
  __syncthreads();
  if (threadIdx.x < 8)
    part[(size_t)blockIdx.x * 8 + threadIdx.x] =
        red[0][threadIdx.x] + red[1][threadIdx.x] + red[2][threadIdx.x] + red[3][threadIdx.x];
  U8 o;
#pragma unroll
  for (int co = 0; co < 8; ++co) o.u[co] = f2bf(acc[co]);
  *(uint4*)(h4raw + (size_t)p * 8) = o.q;
}

// ---------------------------------------------------------------- norm4 + skip2 (1x1 32->8)
__global__ void k_norm4(const unsigned short* __restrict__ h4raw, const unsigned short* __restrict__ blkpad,
                        const float* __restrict__ scale, const float* __restrict__ shift,
                        const float* __restrict__ sw2, const float* __restrict__ sb2,
                        unsigned short* __restrict__ blk2pad) {
  __shared__ float wl[256];
  {
    int i = threadIdx.x;
    int ci = i >> 3, co = i & 7;
    wl[i] = sw2[co * 32 + ci];
  }
  __syncthreads();
  int p = blockIdx.x * 256 + threadIdx.x;
  int b = p / HW, r = p % HW, y = r / W, xx = r % W;
  float acc[8];
#pragma unroll
  for (int co = 0; co < 8; ++co) acc[co] = sb2[co];
  size_t cbase = ((size_t)(b * IH3 + y + 1) * P3 + (xx + 1));
  const unsigned short* bp = blkpad + cbase * 32;
#pragma unroll
  for (int half = 0; half < 4; ++half) {
    U8 u; u.q = *(const uint4*)(bp + half * 8);
#pragma unroll
    for (int j = 0; j < 8; ++j) {
      float iv = bf2f(u.u[j]);
      int ci = half * 8 + j;
#pragma unroll
      for (int co = 0; co < 8; ++co) acc[co] += iv * wl[ci * 8 + co];
    }
  }
  U8 hv; hv.q = *(const uint4*)(h4raw + (size_t)p * 8);
  U8 o;
#pragma unroll
  for (int co = 0; co < 8; ++co) {
    float f = fmaxf(bf2f(hv.u[co]) * scale[b * 8 + co] + shift[b * 8 + co], 0.0f) + acc[co];
    o.u[co] = f2bf(f);
  }
  *(uint4*)(blk2pad + cbase * 8) = o.q;
}

// ---------------------------------------------------------------- conv5 direct (8->2, 3x3)
__global__ void k_conv5(const unsigned short* __restrict__ blk2pad, const float* __restrict__ w5,
                        const float* __restrict__ b5, float* __restrict__ h5) {
  __shared__ float wl[144];
  if (threadIdx.x < 144) {
    int i = threadIdx.x;
    int t = i / 16, r2 = i % 16, ci = r2 >> 1, co = r2 & 1;
    wl[i] = w5[(co * 8 + ci) * 9 + t];
  }
  __syncthreads();
  int p = blockIdx.x * 256 + threadIdx.x;
  int b = p / HW, r = p % HW, y = r / W, xx = r % W;
  float a0 = b5[0], a1 = b5[1];
#pragma unroll
  for (int t = 0; t < 9; ++t) {
    int ky = t / 3, kx = t % 3;
    const unsigned short* ip = blk2pad + ((size_t)(b * IH3 + y + ky) * P3 + (xx + kx)) * 8;
    U8 u; u.q = *(const uint4*)ip;
#pragma unroll
    for (int ci = 0; ci < 8; ++ci) {
      float iv = bf2f(u.u[ci]);
      a0 += iv * wl[t * 16 + ci * 2];
      a1 += iv * wl[t * 16 + ci * 2 + 1];
    }
  }
  h5[(size_t)p * 2] = a0;
  h5[(size_t)p * 2 + 1] = a1;
}

// ---------------------------------------------------------------- joint bilateral + tanh + scale
__global__ void k_bilateral(const float* __restrict__ h5, const float* __restrict__ x,
                            float* __restrict__ out, int nTot) {
  int p = blockIdx.x * 256 + threadIdx.x;
  if (p >= nTot) return;
  int b = p / HW, r = p % HW, y = r / W, xx = r % W;
  const float* xb = x + (size_t)b * HW;
  float xc = xb[r];
  float e1 = expf(-1.0f / 4.5f), e0 = expf(-4.0f / 4.5f);
  float gs = 1.0f + 2.0f * e1 + 2.0f * e0;
  float g[5] = {e0 / gs, e1 / gs, 1.0f / gs, e1 / gs, e0 / gs};
  float n0 = 0.0f, n1 = 0.0f, den = 0.0f;
#pragma unroll
  for (int dy = 0; dy < 5; ++dy) {
    int yn = y + dy - 2;
    yn = yn < 0 ? -yn : (yn >= H ? 2 * H - 2 - yn : yn);
#pragma unroll
    for (int dx = 0; dx < 5; ++dx) {
      int xn = xx + dx - 2;
      xn = xn < 0 ? -xn : (xn >= W ? 2 * W - 2 - xn : xn);
      float xv = xb[yn * W + xn];
      float d = xv - xc;
      float wgt = g[dy] * g[dx] * expf(-200.0f * d * d);
      den += wgt;
      const float* hp = h5 + ((size_t)(b * HW) + yn * W + xn) * 2;
      n0 += wgt * hp[0];
      n1 += wgt * hp[1];
    }
  }
  float o0 = tanhf(n0 / den) * 0.436f;
  float o1 = tanhf(n1 / den) * 0.615f;
  out[(size_t)(b * 2) * HW + r] = o0;
  out[(size_t)(b * 2 + 1) * HW + r] = o1;
}

// ---------------------------------------------------------------- host
extern "C" void kernel_launch(void* const* d_in, const int* in_sizes, int n_in,
                              void* d_out, int out_size, void* d_ws, size_t ws_size,
                              hipStream_t stream) {
  (void)in_sizes; (void)n_in; (void)out_size;
  const float* x   = (const float*)d_in[0];
  const float* w1  = (const float*)d_in[1];
  const float* b1  = (const float*)d_in[2];
  const float* g1w = (const float*)d_in[3];
  const float* g1b = (const float*)d_in[4];
  const float* w2  = (const float*)d_in[5];
  const float* b2  = (const float*)d_in[6];
  const float* g2w = (const float*)d_in[7];
  const float* g2b = (const float*)d_in[8];
  const float* w3  = (const float*)d_in[9];
  const float* b3  = (const float*)d_in[10];
  const float* g3w = (const float*)d_in[11];
  const float* g3b = (const float*)d_in[12];
  const float* w4  = (const float*)d_in[13];
  const float* b4  = (const float*)d_in[14];
  const float* g4w = (const float*)d_in[15];
  const float* g4b = (const float*)d_in[16];
  const float* w5  = (const float*)d_in[17];
  const float* b5  = (const float*)d_in[18];
  const float* sw1 = (const float*)d_in[19];
  const float* sb1 = (const float*)d_in[20];
  const float* sw2 = (const float*)d_in[21];
  const float* sb2 = (const float*)d_in[22];
  float* out = (float*)d_out;
  char* ws = (char*)d_ws;

  auto AL = [](size_t v) { return (v + 255) & ~(size_t)255; };
  const size_t sSPAD  = (size_t)IH5 * P5 * 128 * 2;
  const size_t sANG   = (size_t)HW * 8 * 4;
  const size_t sH1RAW = (size_t)HW * 64 * 2;
  const size_t sH1PAD = (size_t)IH3 * P3 * 64 * 2;
  const size_t sH2RAW = (size_t)HW * 32 * 2;
  const size_t sBLKP  = (size_t)IH3 * P3 * 32 * 2;
  const size_t sH3RAW = (size_t)HW * 16 * 2;
  const size_t sH3PAD = (size_t)IH3 * P3 * 16 * 2;
  const size_t sH4RAW = (size_t)HW * 8 * 2;
  const size_t sBLK2  = (size_t)IH3 * P3 * 8 * 2;

  // choose largest batch-chunk that fits the workspace
  int nb = 0;
  size_t offB = 0, offH1PAD = 0, offSmall = 0;
  const size_t smallFixed = AL(1024 * 1024) + AL((size_t)4 * 1080 * 16 * 4) + 8 * 4096;
  for (int cand = 4; cand >= 1; cand >>= 1) {
    size_t oB   = AL((size_t)cand * sSPAD);
    size_t oH1P = AL(oB + (size_t)cand * sH1RAW);
    size_t oS   = AL(oH1P + (size_t)cand * sH1PAD);
    size_t need = oS + smallFixed + AL((size_t)cand * sH2RAW);   // + dedicated sk1
    if (ws_size >= need) { nb = cand; offB = oB; offH1PAD = oH1P; offSmall = oS; break; }
  }
  if (nb == 0) {
    k_fill<<<(BN * 2 * HW + 255) / 256, 256, 0, stream>>>(out, BN * 2 * HW, 123.0f);
    return;
  }

  size_t oWB1  = offSmall;
  size_t oWB2  = AL(oWB1 + 25 * 64 * 128 * 2);
  size_t oWB3  = AL(oWB2 + 9 * 32 * 64 * 2);
  size_t oWBS  = AL(oWB3 + 9 * 16 * 32 * 2);
  size_t oPART = AL(oWBS + 32 * 128 * 2);
  size_t oSC1  = AL(oPART + (size_t)4 * 1080 * 16 * 4);
  size_t oSC2  = oSC1 + 4096, oSC3 = oSC2 + 4096, oSC4 = oSC3 + 4096;
  size_t oSK1  = oSC4 + 4096;

  unsigned short* wb1  = (unsigned short*)(ws + oWB1);
  unsigned short* wb2  = (unsigned short*)(ws + oWB2);
  unsigned short* wb3  = (unsigned short*)(ws + oWB3);
  unsigned short* wbs1 = (unsigned short*)(ws + oWBS);
  float* part = (float*)(ws + oPART);
  float* sc1 = (float*)(ws + oSC1); float* sh1 = sc1 + nb * 64;
  float* sc2 = (float*)(ws + oSC2); float* sh2 = sc2 + nb * 32;
  float* sc3 = (float*)(ws + oSC3); float* sh3 = sc3 + nb * 16;
  float* sc4 = (float*)(ws + oSC4); float* sh4 = sc4 + nb * 8;
  unsigned short* sk1 = (unsigned short*)(ws + oSK1);

  k_prep<128, 64, 5><<<800, 256, 0, stream>>>(w1, wb1);
  k_prep<64, 32, 3><<<72, 256, 0, stream>>>(w2, wb2);
  k_prep<32, 16, 3><<<18, 256, 0, stream>>>(w3, wb3);
  k_prep<128, 32, 1><<<16, 256, 0, stream>>>(sw1, wbs1);

  // tail-region offsets inside the (dead-after-conv1) spad region
  size_t t0 = AL((size_t)nb * sBLKP);
  size_t t1 = AL(t0 + (size_t)nb * sH3RAW);
  size_t t2 = AL(t1 + (size_t)nb * sH3PAD);
  size_t t3 = AL(t2 + (size_t)nb * sH4RAW);
  size_t t4 = AL(t3 + (size_t)nb * sBLK2);

  for (int b0 = 0; b0 < BN; b0 += nb) {
    const float* x_c = x + (size_t)b0 * HW;
    float* out_c = out + (size_t)b0 * 2 * HW;
    unsigned short* spad   = (unsigned short*)(ws);
    float*          ang    = (float*)(ws + offB);
    float*          pooled = (float*)(ws + AL(offB + (size_t)nb * sANG));
    unsigned short* h1raw  = (unsigned short*)(ws + offB);
    unsigned short* h1pad  = (unsigned short*)(ws + offH1PAD);
    unsigned short* h2raw  = (unsigned short*)(ws + offB);
    unsigned short* blkpad = (unsigned short*)(ws);
    unsigned short* h3raw  = (unsigned short*)(ws + t0);
    unsigned short* h3pad  = (unsigned short*)(ws + t1);
    unsigned short* h4raw  = (unsigned short*)(ws + t2);
    unsigned short* blk2   = (unsigned short*)(ws + t3);
    float*          h5     = (float*)(ws + t4);
    int nHW = nb * HW;

    hipMemsetAsync(spad, 0, (size_t)nb * sSPAD, stream);
    hipMemsetAsync(h1pad, 0, (size_t)nb * sH1PAD, stream);

    k_sift_ang<<<nb * 540, 256, 0, stream>>>(x_c, ang, nHW);
    int nPP = nb * (H + 1) * (W + 1);
    k_sift_pool<<<(nPP + 255) / 256, 256, 0, stream>>>(ang, pooled, nPP);
    k_sift_desc<<<nHW / 4, 256, 0, stream>>>(pooled, spad);

    // conv1 (5x5, 128->64) with fused skip1 (1x1 128->32)
    k_conv_slab<128, 64, 5, 8, true><<<nb * 1080, 256, 0, stream>>>(
        spad, IH5, P5, wb1, b1, wbs1, sb1, h1raw, sk1, part);
    k_gn_fin<64, 8><<<nb * 8, 64, 0, stream>>>(part, 1080, g1w, g1b, sc1, sh1, 1.0f / (8.0f * HW));
    k_norm<64, false><<<nb * 4320, 256, 0, stream>>>(h1raw, nullptr, sc1, sh1, h1pad);

    k_conv_slab<64, 32, 3, 8, false><<<nb * 1080, 256, 0, stream>>>(
        h1pad, IH3, P3, wb2, b2, nullptr, nullptr, h2raw, nullptr, part);
    k_gn_fin<32, 8><<<nb * 8, 64, 0, stream>>>(part, 1080, g2w, g2b, sc2, sh2, 1.0f / (4.0f * HW));

    // spad is dead now; its region hosts blkpad + tail buffers
    hipMemsetAsync(blkpad, 0, (size_t)nb * sBLKP, stream);
    hipMemsetAsync(h3pad, 0, (size_t)nb * sH3PAD, stream);
    hipMemsetAsync(blk2, 0, (size_t)nb * sBLK2, stream);

    k_norm<32, true><<<nb * 2160, 256, 0, stream>>>(h2raw, sk1, sc2, sh2, blkpad);

    k_conv_slab<32, 16, 3, 4, false><<<nb * 1080, 256, 0, stream>>>(
        blkpad, IH3, P3, wb3, b3, nullptr, nullptr, h3raw, nullptr, part);
    k_gn_fin<16, 4><<<nb * 4, 64, 0, stream>>>(part, 1080, g3w, g3b, sc3, sh3, 1.0f / (4.0f * HW));
    k_norm<16, false><<<nb * 1080, 256, 0, stream>>>(h3raw, nullptr, sc3, sh3, h3pad);

    k_conv4<<<nb * 540, 256, 0, stream>>>(h3pad, w4, b4, h4raw, part);
    k_gn_fin<8, 4><<<nb * 4, 64, 0, stream>>>(part, 540, g4w, g4b, sc4, sh4, 1.0f / (2.0f * HW));
    k_norm4<<<nb * 540, 256, 0, stream>>>(h4raw, blkpad, sc4, sh4, sw2, sb2, blk2);

    k_conv5<<<nb * 540, 256, 0, stream>>>(blk2, w5, b5, h5);
    k_bilateral<<<nb * 540, 256, 0, stream>>>(h5, x_c, out_c, nHW);
  }
}